// Round 1
// baseline (780.254 us; speedup 1.0000x reference)
//
#include <hip/hip_runtime.h>
#include <hip/hip_bf16.h>
#include <stdint.h>

constexpr int BH  = 16;    // batch*head
constexpr int LEN = 2048;
constexpr int DK  = 128;
constexpr int RND = 4;
constexpr int NB2 = 16;    // n_buckets/2 (chunk count)
constexpr int BL2 = 128;   // queries per chunk

__device__ __forceinline__ float bflo(uint32_t u){ return __uint_as_float(u << 16); }
__device__ __forceinline__ float bfhi(uint32_t u){ return __uint_as_float(u & 0xffff0000u); }
__device__ __forceinline__ uint16_t f2b(float x){
  uint32_t u = __float_as_uint(x);
  return (uint16_t)((u + 0x7fffu + ((u >> 16) & 1u)) >> 16);   // RNE
}

// ---------------- kernel 1: normalize q, bf16 copies, LSH hash ----------------
__global__ __launch_bounds__(64) void k_hash(const float* __restrict__ q,
    const float* __restrict__ v, const float* __restrict__ rm,
    uint16_t* __restrict__ fqb, uint16_t* __restrict__ vbb,
    uint8_t* __restrict__ hsh)
{
  int bid = blockIdx.x;                 // b*LEN + l
  int b = bid >> 11, l = bid & (LEN-1);
  int t = threadIdx.x;
  __shared__ float sfq[DK];
  __shared__ float sh[64];
  size_t ro = (size_t)bid * DK;
  float2 qv = ((const float2*)(q + ro))[t];
  float ss = qv.x*qv.x + qv.y*qv.y;
  #pragma unroll
  for (int off=32; off>0; off>>=1) ss += __shfl_xor(ss, off);
  float rn = 1.0f / sqrtf(ss);
  float f0 = qv.x*rn, f1 = qv.y*rn;
  sfq[2*t] = f0; sfq[2*t+1] = f1;
  fqb[ro + 2*t] = f2b(f0); fqb[ro + 2*t + 1] = f2b(f1);
  float2 vv = ((const float2*)(v + ro))[t];
  vbb[ro + 2*t] = f2b(vv.x); vbb[ro + 2*t + 1] = f2b(vv.y);
  __syncthreads();
  int r = t >> 4, k = t & 15;
  const float* rmb = rm + (size_t)b*DK*RND*NB2 + r*NB2 + k;
  float dot = 0.f, s2 = 0.f;
  for (int d=0; d<DK; d++){ float w = rmb[(size_t)d*RND*NB2]; dot += sfq[d]*w; s2 += w*w; }
  sh[t] = dot / sqrtf(s2);
  __syncthreads();
  if (t < RND){
    float best = -INFINITY; int bi = 0;
    for (int k2=0;k2<NB2;k2++){ float hv =  sh[t*NB2+k2]; if (hv > best){best=hv;bi=k2;} }
    for (int k2=0;k2<NB2;k2++){ float hv = -sh[t*NB2+k2]; if (hv > best){best=hv;bi=k2+NB2;} }
    hsh[(size_t)(b*RND + t)*LEN + l] = (uint8_t)bi;
  }
}

// ---------------- kernel 2: stable counting sort per (b,r) ----------------
__global__ __launch_bounds__(256) void k_sort(const uint8_t* __restrict__ hsh,
    int* __restrict__ posA, int* __restrict__ tokA)
{
  __shared__ int hist[32*256];
  __shared__ int sums[256];
  int br = blockIdx.x;
  int t = threadIdx.x;
  const uint8_t* hh = hsh + (size_t)br*LEN;
  uint8_t ub[8];
  #pragma unroll
  for (int i=0;i<8;i++) ub[i] = hh[t*8+i];
  #pragma unroll
  for (int k=0;k<32;k++) hist[k*256+t] = 0;
  __syncthreads();
  #pragma unroll
  for (int i=0;i<8;i++) hist[(int)ub[i]*256 + t] += 1;   // column t private to thread t
  __syncthreads();
  int base = t*32, s0 = 0;
  for (int e=0;e<32;e++) s0 += hist[base+e];
  sums[t] = s0;
  __syncthreads();
  if (t == 0){
    int run = 0;
    for (int i=0;i<256;i++){ int tmp = sums[i]; sums[i] = run; run += tmp; }
  }
  __syncthreads();
  int run = sums[t];
  for (int e=0;e<32;e++){ int tmp = hist[base+e]; hist[base+e] = run; run += tmp; }
  __syncthreads();
  #pragma unroll
  for (int i=0;i<8;i++){
    int l = t*8+i, k = ub[i];
    int p = hist[k*256+t]++;
    posA[(size_t)br*LEN + l] = p;
    tokA[(size_t)br*LEN + p] = l;
  }
}

// ---------------- kernel 2b: pack meta = tok | bucket<<11 | chunkcode<<16 ----------------
__global__ __launch_bounds__(256) void k_meta(const uint8_t* __restrict__ hsh,
    const int* __restrict__ posA, const int* __restrict__ tokA, int* __restrict__ meta)
{
  int idx = blockIdx.x*256 + threadIdx.x;   // over BH*RND*LEN (sorted positions)
  int br = idx >> 11;
  int b = br >> 2;
  int tok = tokA[idx];
  int bucket = hsh[(size_t)br*LEN + tok];
  int code = 0;
  #pragma unroll
  for (int r2=0;r2<4;r2++){
    int p = posA[(size_t)(b*4+r2)*LEN + tok];
    code |= (p >> 7) << (4*r2);              // chunk id in [0,16)
  }
  meta[idx] = tok | (bucket<<11) | (code<<16);
}

// ---------------- shared tile helpers ----------------
__device__ __forceinline__ float masked_score(float dot, int mq, int mk){
  int tq = mq & 2047, tk = mk & 2047;
  float x = dot * 0.08838834764831845f;      // 1/sqrt(128)
  if (((mq ^ mk) & (31<<11)) != 0) x = -1e9f;   // different bucket
  if (tq < tk)  x = -1e9f;                      // causal
  if (tq == tk) x = -1e5f;                      // self
  uint32_t cq = ((uint32_t)mq) >> 16, ck = ((uint32_t)mk) >> 16;
  int cnt = 0;
  #pragma unroll
  for (int r2=0;r2<4;r2++){
    uint32_t a = (cq >> (4*r2)) & 15u, b2 = (ck >> (4*r2)) & 15u;
    cnt += (int)((b2 == a) | (b2 == ((a+15u)&15u)));
  }
  float lg = (cnt==1)?0.f:((cnt==2)?0.69314718f:((cnt==3)?1.09861229f:1.38629436f));
  return x - lg;
}

__device__ __forceinline__ void stage_q(uint16_t* Qs, const uint16_t* fqb,
    const int* meta, int sbase, int qs0, int b, int t)
{
  int row = t >> 1, half = t & 1;
  int tok = meta[sbase + qs0 + row] & 2047;
  const uint4* src = (const uint4*)(fqb + ((size_t)b*LEN + tok)*DK + half*64);
  uint32_t* qrow = (uint32_t*)(Qs + row*DK);
  int sw = (row>>2)&7;
  #pragma unroll
  for (int g=0; g<8; g++){
    uint4 w = src[g];
    int c = half*32 + g*4;
    qrow[(c+0)^sw]=w.x; qrow[(c+1)^sw]=w.y; qrow[(c+2)^sw]=w.z; qrow[(c+3)^sw]=w.w;
  }
}

__device__ __forceinline__ int stage_k(uint16_t* Ks, const uint16_t* srcbuf,
    const int* meta, int sbase, int n, int c, int b, int t, int tok_in)
{
  int row = t >> 2, q4 = t & 3;
  int tok = tok_in;
  if (tok < 0){
    int jg = c*64 + row;
    int sk = (jg < BL2) ? (((n+NB2-1)&(NB2-1))*BL2 + jg) : (n*BL2 + jg - BL2);
    tok = meta[sbase + sk] & 2047;
  }
  const uint4* src = (const uint4*)(srcbuf + ((size_t)b*LEN + tok)*DK) + q4*4;
  uint32_t* krow = (uint32_t*)(Ks + row*DK);
  int sw = (row>>3)&7;
  #pragma unroll
  for (int g=0; g<4; g++){
    uint4 w = src[g];
    int cc = q4*16 + g*4;
    krow[(cc+0)^sw]=w.x; krow[(cc+1)^sw]=w.y; krow[(cc+2)^sw]=w.z; krow[(cc+3)^sw]=w.w;
  }
  return tok;
}

__device__ __forceinline__ void dot_tile(const uint16_t* Qs, const uint16_t* Ks,
    int ti, int tj, float acc[4][8])
{
  #pragma unroll
  for (int ii=0;ii<4;ii++)
    #pragma unroll
    for (int jj=0;jj<8;jj++) acc[ii][jj] = 0.f;
  int swq = ti & 7;
  const uint32_t* qb = (const uint32_t*)Qs;
  const uint32_t* kb = (const uint32_t*)Ks;
  for (int dp=0; dp<64; dp++){
    float qx[4], qy[4];
    #pragma unroll
    for (int ii=0;ii<4;ii++){
      uint32_t u = qb[(ti*4+ii)*64 + (dp ^ swq)];
      qx[ii] = bflo(u); qy[ii] = bfhi(u);
    }
    #pragma unroll
    for (int jj=0;jj<8;jj++){
      uint32_t u = kb[(tj*8+jj)*64 + (dp ^ tj)];
      float kx = bflo(u), ky = bfhi(u);
      #pragma unroll
      for (int ii=0;ii<4;ii++) acc[ii][jj] += qx[ii]*kx + qy[ii]*ky;
    }
  }
}

// ---------------- kernel A: per-(b,r,chunk) masked scores -> per-row (max,sumexp) ----------------
__global__ __launch_bounds__(256) void k_stats(const uint16_t* __restrict__ fqb,
    const int* __restrict__ meta, float* __restrict__ rowmax, float* __restrict__ rowsum)
{
  __shared__ uint16_t Qs[BL2*DK];
  __shared__ uint16_t Ks[64*DK];
  __shared__ float2 red[BL2*8];
  int bid = blockIdx.x;
  int n = bid & (NB2-1), r = (bid>>4)&3, b = bid>>6;
  int t = threadIdx.x, ti = t>>3, tj = t&7;
  int sbase = (b*RND + r)*LEN;
  int qs0 = n*BL2;
  stage_q(Qs, fqb, meta, sbase, qs0, b, t);
  int qm[4];
  #pragma unroll
  for (int ii=0;ii<4;ii++) qm[ii] = meta[sbase + qs0 + ti*4 + ii];
  float runM = -INFINITY, runS = 0.f;       // valid in threads t<128 (row = t)
  for (int c=0;c<4;c++){
    __syncthreads();
    stage_k(Ks, fqb, meta, sbase, n, c, b, t, -1);
    int km[8];
    #pragma unroll
    for (int jj=0;jj<8;jj++){
      int jg = c*64 + tj*8 + jj;
      int sk = (jg < BL2) ? (((n+NB2-1)&(NB2-1))*BL2 + jg) : (n*BL2 + jg - BL2);
      km[jj] = meta[sbase + sk];
    }
    __syncthreads();
    float acc[4][8];
    dot_tile(Qs, Ks, ti, tj, acc);
    #pragma unroll
    for (int ii=0;ii<4;ii++){
      float lm = -INFINITY, ls = 0.f;
      #pragma unroll
      for (int jj=0;jj<8;jj++){
        float x = masked_score(acc[ii][jj], qm[ii], km[jj]);
        if (x > lm){ ls = ls*expf(lm - x) + 1.f; lm = x; }
        else        ls += expf(x - lm);
      }
      red[(ti*4+ii)*8 + tj] = make_float2(lm, ls);
    }
    __syncthreads();
    if (t < BL2){
      float M = runM, S = runS;
      #pragma unroll
      for (int p2=0;p2<8;p2++){
        float2 v2 = red[t*8+p2];
        float nM = fmaxf(M, v2.x);
        S = S*expf(M - nM) + v2.y*expf(v2.x - nM);
        M = nM;
      }
      runM = M; runS = S;
    }
  }
  if (t < BL2){
    rowmax[(size_t)sbase + qs0 + t] = runM;
    rowsum[(size_t)sbase + qs0 + t] = runS;
  }
}

// ---------------- kernel B: merge 4 rounds per token -> global (M, 1/S) ----------------
__global__ __launch_bounds__(256) void k_comb(const int* __restrict__ posA,
    const float* __restrict__ rowmax, const float* __restrict__ rowsum,
    float* __restrict__ Mg, float* __restrict__ iSg)
{
  int idx = blockIdx.x*256 + threadIdx.x;  // BH*LEN
  int b = idx >> 11, l = idx & (LEN-1);
  float m[4], s[4], M = -INFINITY;
  #pragma unroll
  for (int r=0;r<4;r++){
    int sp = posA[(size_t)(b*4+r)*LEN + l];
    m[r] = rowmax[(size_t)(b*4+r)*LEN + sp];
    s[r] = rowsum[(size_t)(b*4+r)*LEN + sp];
    M = fmaxf(M, m[r]);
  }
  float S = 0.f;
  #pragma unroll
  for (int r=0;r<4;r++) S += s[r]*expf(m[r] - M);
  Mg[idx] = M;
  iSg[idx] = 1.0f / S;
}

// ---------------- kernel C: recompute scores -> p -> p x V, per round ----------------
__global__ __launch_bounds__(256) void k_attn(const uint16_t* __restrict__ fqb,
    const uint16_t* __restrict__ vbb, const int* __restrict__ meta,
    const float* __restrict__ Mg, const float* __restrict__ iSg,
    float* __restrict__ att)
{
  __shared__ uint16_t Qs[BL2*DK];   // 32 KB
  __shared__ uint16_t KV[64*DK];    // 16 KB (K then V per chunk)
  __shared__ uint16_t Ps[64*BL2];   // 16 KB
  int bid = blockIdx.x;
  int n = bid & (NB2-1), r = (bid>>4)&3, b = bid>>6;
  int t = threadIdx.x, ti = t>>3, tj = t&7;
  int sbase = (b*RND + r)*LEN;
  int qs0 = n*BL2;
  stage_q(Qs, fqb, meta, sbase, qs0, b, t);
  int qm[4]; float Mq[4], iSq[4];
  #pragma unroll
  for (int ii=0;ii<4;ii++){
    qm[ii] = meta[sbase + qs0 + ti*4 + ii];
    int tq = qm[ii] & 2047;
    Mq[ii]  = Mg[(size_t)b*LEN + tq];
    iSq[ii] = iSg[(size_t)b*LEN + tq];
  }
  float att_acc[4][16];
  #pragma unroll
  for (int ii=0;ii<4;ii++)
    #pragma unroll
    for (int d=0;d<16;d++) att_acc[ii][d] = 0.f;

  for (int c=0;c<4;c++){
    __syncthreads();
    int ktok = stage_k(KV, fqb, meta, sbase, n, c, b, t, -1);
    int km[8];
    #pragma unroll
    for (int jj=0;jj<8;jj++){
      int jg = c*64 + tj*8 + jj;
      int sk = (jg < BL2) ? (((n+NB2-1)&(NB2-1))*BL2 + jg) : (n*BL2 + jg - BL2);
      km[jj] = meta[sbase + sk];
    }
    __syncthreads();
    float acc[4][8];
    dot_tile(Qs, KV, ti, tj, acc);
    #pragma unroll
    for (int ii=0;ii<4;ii++)
      #pragma unroll
      for (int jj=0;jj<8;jj++){
        float x = masked_score(acc[ii][jj], qm[ii], km[jj]);
        float p = expf(x - Mq[ii]) * iSq[ii];
        Ps[(tj*8+jj)*BL2 + ti*4 + ii] = f2b(p);
      }
    __syncthreads();            // dot reads done + Ps visible
    stage_k(KV, vbb, meta, sbase, n, c, b, t, ktok);   // overwrite K with V
    __syncthreads();
    for (int j2=0; j2<64; j2++){
      const uint32_t* prow = (const uint32_t*)(Ps + j2*BL2);
      uint32_t pu0 = prow[ti*2], pu1 = prow[ti*2+1];
      float p0=bflo(pu0), p1=bfhi(pu0), p2v=bflo(pu1), p3=bfhi(pu1);
      const uint32_t* vrow = (const uint32_t*)(KV + j2*DK);
      int swv = (j2>>3)&7;
      #pragma unroll
      for (int q=0;q<8;q++){
        uint32_t u = vrow[(tj*8+q)^swv];
        float vx = bflo(u), vy = bfhi(u);
        att_acc[0][2*q] += p0*vx;  att_acc[0][2*q+1] += p0*vy;
        att_acc[1][2*q] += p1*vx;  att_acc[1][2*q+1] += p1*vy;
        att_acc[2][2*q] += p2v*vx; att_acc[2][2*q+1] += p2v*vy;
        att_acc[3][2*q] += p3*vx;  att_acc[3][2*q+1] += p3*vy;
      }
    }
  }
  #pragma unroll
  for (int ii=0;ii<4;ii++){
    float* dst = att + ((size_t)(sbase + qs0 + ti*4 + ii))*DK + tj*16;
    #pragma unroll
    for (int q=0;q<4;q++)
      ((float4*)dst)[q] = make_float4(att_acc[ii][4*q], att_acc[ii][4*q+1],
                                      att_acc[ii][4*q+2], att_acc[ii][4*q+3]);
  }
}

// ---------------- kernel D: gather + sum rounds back to original order ----------------
__global__ __launch_bounds__(128) void k_out(const float* __restrict__ att,
    const int* __restrict__ posA, float* __restrict__ out)
{
  int bid = blockIdx.x;               // b*LEN + l
  int b = bid >> 11, l = bid & (LEN-1);
  int t = threadIdx.x;
  float s = 0.f;
  #pragma unroll
  for (int r=0;r<4;r++){
    int sp = posA[(size_t)(b*RND+r)*LEN + l];
    s += att[((size_t)(b*RND+r)*LEN + sp)*DK + t];
  }
  out[(size_t)bid*DK + t] = s;
}

extern "C" void kernel_launch(void* const* d_in, const int* in_sizes, int n_in,
                              void* d_out, int out_size, void* d_ws, size_t ws_size,
                              hipStream_t stream)
{
  const float* q  = (const float*)d_in[0];
  const float* v  = (const float*)d_in[1];
  // d_in[2] = mask (all true), d_in[4] = seed: unused by the reference math here
  const float* rm = (const float*)d_in[3];
  float* out = (float*)d_out;

  char* w = (char*)d_ws;
  uint16_t* fqb = (uint16_t*)w;                                   // 8 MiB normalized q, bf16
  uint16_t* vbb = (uint16_t*)(w + (size_t)8*1024*1024);           // 8 MiB value, bf16
  uint8_t*  hsh = (uint8_t*)(w + (size_t)16*1024*1024);           // 128 KiB
  int* posA = (int*)(w + (size_t)16*1024*1024 + 131072);          // [BH][R][LEN]
  int* tokA = posA + BH*RND*LEN;
  int* meta = tokA + BH*RND*LEN;
  float* rowmax = (float*)(meta + BH*RND*LEN);
  float* rowsum = rowmax + BH*RND*LEN;
  float* Mg  = rowsum + BH*RND*LEN;
  float* iSg = Mg + BH*LEN;
  float* att = iSg + BH*LEN;                                      // 64 MiB

  k_hash <<<dim3(BH*LEN),      dim3(64),  0, stream>>>(q, v, rm, fqb, vbb, hsh);
  k_sort <<<dim3(BH*RND),      dim3(256), 0, stream>>>(hsh, posA, tokA);
  k_meta <<<dim3(BH*RND*LEN/256), dim3(256), 0, stream>>>(hsh, posA, tokA, meta);
  k_stats<<<dim3(BH*RND*NB2),  dim3(256), 0, stream>>>(fqb, meta, rowmax, rowsum);
  k_comb <<<dim3(BH*LEN/256),  dim3(256), 0, stream>>>(posA, rowmax, rowsum, Mg, iSg);
  k_attn <<<dim3(BH*RND*NB2),  dim3(256), 0, stream>>>(fqb, vbb, meta, Mg, iSg, att);
  k_out  <<<dim3(BH*LEN),      dim3(128), 0, stream>>>(att, posA, out);
}

// Round 2
// 238.492 us; speedup vs baseline: 3.2716x; 3.2716x over previous
//
#include <hip/hip_runtime.h>
#include <hip/hip_bf16.h>
#include <stdint.h>

constexpr int BH  = 16;    // batch*head
constexpr int LEN = 2048;
constexpr int DK  = 128;
constexpr int RND = 4;
constexpr int NB2 = 16;    // n_buckets/2 (chunk count)
constexpr int BL2 = 128;   // queries per chunk
constexpr int KC  = 32;    // keys per inner iteration (8 iterations cover 256-key window)

typedef __attribute__((ext_vector_type(8))) short short8;
typedef __attribute__((ext_vector_type(4))) float f32x4;

__device__ __forceinline__ float bflo(uint32_t u){ return __uint_as_float(u << 16); }
__device__ __forceinline__ uint16_t f2b(float x){
  uint32_t u = __float_as_uint(x);
  return (uint16_t)((u + 0x7fffu + ((u >> 16) & 1u)) >> 16);   // RNE
}

// ---------------- kernel 0: inverse norms of rand_matrix columns ----------------
__global__ __launch_bounds__(64) void k_rmn(const float* __restrict__ rm,
                                            float* __restrict__ invn)
{
  int b = blockIdx.x, t = threadIdx.x;       // t = r*16+k
  const float* p = rm + (size_t)b*DK*RND*NB2 + t;
  float s2 = 0.f;
  #pragma unroll 8
  for (int d=0; d<DK; d++){ float w = p[(size_t)d*64]; s2 += w*w; }
  invn[b*64 + t] = 1.0f / sqrtf(s2);
}

// ---------------- kernel 1: normalize q, bf16 copies, LSH hash ----------------
__global__ __launch_bounds__(64) void k_hash(const float* __restrict__ q,
    const float* __restrict__ v, const float* __restrict__ rm,
    const float* __restrict__ invn,
    uint16_t* __restrict__ fqb, uint16_t* __restrict__ vbb,
    uint8_t* __restrict__ hsh)
{
  int bid = blockIdx.x;                 // b*LEN + l
  int b = bid >> 11, l = bid & (LEN-1);
  int t = threadIdx.x;
  __shared__ float sfq[DK];
  __shared__ float sh[64];
  size_t ro = (size_t)bid * DK;
  float2 qv = ((const float2*)(q + ro))[t];
  float ss = qv.x*qv.x + qv.y*qv.y;
  #pragma unroll
  for (int off=32; off>0; off>>=1) ss += __shfl_xor(ss, off);
  float rn = 1.0f / sqrtf(ss);
  float f0 = qv.x*rn, f1 = qv.y*rn;
  sfq[2*t] = f0; sfq[2*t+1] = f1;
  fqb[ro + 2*t] = f2b(f0); fqb[ro + 2*t + 1] = f2b(f1);
  float2 vv = ((const float2*)(v + ro))[t];
  vbb[ro + 2*t] = f2b(vv.x); vbb[ro + 2*t + 1] = f2b(vv.y);
  __syncthreads();
  const float* rmb = rm + (size_t)b*DK*RND*NB2 + t;
  float dot = 0.f;
  #pragma unroll 8
  for (int d=0; d<DK; d++){ dot += sfq[d] * rmb[(size_t)d*64]; }
  sh[t] = dot * invn[b*64 + t];
  __syncthreads();
  if (t < RND){
    float best = -INFINITY; int bi = 0;
    for (int k2=0;k2<NB2;k2++){ float hv =  sh[t*NB2+k2]; if (hv > best){best=hv;bi=k2;} }
    for (int k2=0;k2<NB2;k2++){ float hv = -sh[t*NB2+k2]; if (hv > best){best=hv;bi=k2+NB2;} }
    hsh[(size_t)(b*RND + t)*LEN + l] = (uint8_t)bi;
  }
}

// ---------------- kernel 2: stable counting sort per (b,r) ----------------
__global__ __launch_bounds__(256) void k_sort(const uint8_t* __restrict__ hsh,
    int* __restrict__ posA, int* __restrict__ tokA)
{
  __shared__ int hist[32*256];
  __shared__ int sums[256];
  int br = blockIdx.x;
  int t = threadIdx.x;
  const uint8_t* hh = hsh + (size_t)br*LEN;
  uint8_t ub[8];
  #pragma unroll
  for (int i=0;i<8;i++) ub[i] = hh[t*8+i];
  #pragma unroll
  for (int k=0;k<32;k++) hist[k*256+t] = 0;
  __syncthreads();
  #pragma unroll
  for (int i=0;i<8;i++) hist[(int)ub[i]*256 + t] += 1;
  __syncthreads();
  int base = t*32, s0 = 0;
  for (int e=0;e<32;e++) s0 += hist[base+e];
  sums[t] = s0;
  __syncthreads();
  if (t == 0){
    int run = 0;
    for (int i=0;i<256;i++){ int tmp = sums[i]; sums[i] = run; run += tmp; }
  }
  __syncthreads();
  int run = sums[t];
  for (int e=0;e<32;e++){ int tmp = hist[base+e]; hist[base+e] = run; run += tmp; }
  __syncthreads();
  #pragma unroll
  for (int i=0;i<8;i++){
    int l = t*8+i, k = ub[i];
    int p = hist[k*256+t]++;
    posA[(size_t)br*LEN + l] = p;
    tokA[(size_t)br*LEN + p] = l;
  }
}

// ---------------- kernel 2b: pack meta = tok | bucket<<11 | chunkcode<<16 ----------------
__global__ __launch_bounds__(256) void k_meta(const uint8_t* __restrict__ hsh,
    const int* __restrict__ posA, const int* __restrict__ tokA, int* __restrict__ meta)
{
  int idx = blockIdx.x*256 + threadIdx.x;   // over BH*RND*LEN (sorted positions)
  int br = idx >> 11;
  int b = br >> 2;
  int tok = tokA[idx];
  int bucket = hsh[(size_t)br*LEN + tok];
  int code = 0;
  #pragma unroll
  for (int r2=0;r2<4;r2++){
    int p = posA[(size_t)(b*4+r2)*LEN + tok];
    code |= (p >> 7) << (4*r2);              // chunk id in [0,16)
  }
  meta[idx] = tok | (bucket<<11) | (code<<16);
}

__device__ __forceinline__ int sortedKeyIdx(int n, int jg){
  return (jg < BL2) ? (((n+NB2-1)&(NB2-1))*BL2 + jg) : (n*BL2 + jg - BL2);
}

// ---------------- kernel 3: fused MFMA attention, fixed-max softmax ----------------
// Per block: one (b, r, chunk n): 128 q-rows x 256-key window, 8 waves x 16 rows.
// Writes unnormalized O_r (bf16) and row sums S_r; normalization happens in k_out.
// LDS strides: Q/K rows 136 ushort (bank base 4*row mod 32, <=2-way), P/VT 40 ushort.
__global__ __launch_bounds__(512, 4) void k_fattn(
    const uint16_t* __restrict__ fqb, const uint16_t* __restrict__ vbb,
    const int* __restrict__ meta, uint16_t* __restrict__ attb,
    float* __restrict__ rowsum)
{
  __shared__ uint16_t Qs[128*136];   // 34816 B
  __shared__ uint16_t Ks[KC*136];    //  8704 B
  __shared__ uint16_t Ps[128*40];    // 10240 B  (P in A-operand layout: [qrow][key])
  __shared__ uint16_t VT[128*40];    // 10240 B  (V transposed: [d][key])
  __shared__ int qmeta[128];
  __shared__ int kmeta[KC];

  int bid = blockIdx.x;
  int n = bid & (NB2-1), r = (bid>>4)&3, b = bid>>6;
  int t = threadIdx.x;
  int w = t >> 6, lane = t & 63;
  int l16 = lane & 15, quad = lane >> 4;
  int sbase = (b*RND + r)*LEN;
  int qs0 = n*BL2;
  size_t gbase = (size_t)b*LEN;

  if (t < 128) qmeta[t] = meta[sbase + qs0 + t];
  __syncthreads();
  // stage Q (128 rows x 128 d bf16)
  #pragma unroll
  for (int i=0;i<4;i++){
    int ch = t + i*512;
    int row = ch >> 4, c16 = ch & 15;
    int tok = qmeta[row] & 2047;
    uint4 u = *(const uint4*)(fqb + (gbase + tok)*DK + c16*8);
    *(uint4*)(Qs + row*136 + c16*8) = u;
  }
  int qm[4];
  #pragma unroll
  for (int reg=0;reg<4;reg++) qm[reg] = qmeta[16*w + quad*4 + reg];

  f32x4 O[8];
  #pragma unroll
  for (int i=0;i<8;i++) O[i] = (f32x4){0.f,0.f,0.f,0.f};
  float rsp[4] = {0.f,0.f,0.f,0.f};

  for (int c=0;c<8;c++){
    __syncthreads();                        // protect Ks/VT/Ps from previous iteration readers
    {// stage K slice (KC rows x 128 d)
      int row = t >> 4, c16 = t & 15;
      int sk = sortedKeyIdx(n, c*KC + row);
      int km = meta[sbase + sk];
      if (c16 == 0) kmeta[row] = km;
      uint4 u = *(const uint4*)(fqb + (gbase + (km & 2047))*DK + c16*8);
      *(uint4*)(Ks + row*136 + c16*8) = u;
    }
    {// stage V slice TRANSPOSED: VT[d][key]
      int key = t >> 4, dbase = (t & 15)*8;
      int sk = sortedKeyIdx(n, c*KC + key);
      int tok = meta[sbase + sk] & 2047;
      uint4 u = *(const uint4*)(vbb + (gbase + tok)*DK + dbase);
      VT[(dbase+0)*40 + key] = (uint16_t)(u.x & 0xffffu);
      VT[(dbase+1)*40 + key] = (uint16_t)(u.x >> 16);
      VT[(dbase+2)*40 + key] = (uint16_t)(u.y & 0xffffu);
      VT[(dbase+3)*40 + key] = (uint16_t)(u.y >> 16);
      VT[(dbase+4)*40 + key] = (uint16_t)(u.z & 0xffffu);
      VT[(dbase+5)*40 + key] = (uint16_t)(u.z >> 16);
      VT[(dbase+6)*40 + key] = (uint16_t)(u.w & 0xffffu);
      VT[(dbase+7)*40 + key] = (uint16_t)(u.w >> 16);
    }
    __syncthreads();
    // ---- QK^T: wave w -> q rows 16w..16w+15, keys c*32..c*32+31 ----
    f32x4 S0 = {0.f,0.f,0.f,0.f}, S1 = {0.f,0.f,0.f,0.f};
    int qrowb = (16*w + l16)*136;
    #pragma unroll
    for (int dc=0;dc<4;dc++){
      short8 a  = *(const short8*)(Qs + qrowb + dc*32 + quad*8);
      short8 b0 = *(const short8*)(Ks + l16*136 + dc*32 + quad*8);
      short8 b1 = *(const short8*)(Ks + (16+l16)*136 + dc*32 + quad*8);
      S0 = __builtin_amdgcn_mfma_f32_16x16x32_bf16(a, b0, S0, 0, 0, 0);
      S1 = __builtin_amdgcn_mfma_f32_16x16x32_bf16(a, b1, S1, 0, 0, 0);
    }
    // ---- mask + exp(x - M0)/cnt, accumulate row sums, write P (bf16) ----
    int km0 = kmeta[l16], km1 = kmeta[16 + l16];
    #pragma unroll
    for (int nj=0;nj<2;nj++){
      int mk = nj ? km1 : km0;
      f32x4 S = nj ? S1 : S0;
      int tk = mk & 2047;
      uint32_t ck = ((uint32_t)mk) >> 16;
      #pragma unroll
      for (int reg=0;reg<4;reg++){
        int mq = qm[reg];
        int tq = mq & 2047;
        float x = S[reg] * 0.08838834764831845f;       // 1/sqrt(128)
        bool kill = (((mq ^ mk) & (31<<11)) != 0) | (tq < tk);
        if (tq == tk) x = -30.0f;                      // self: representable tiny weight
        uint32_t cq = ((uint32_t)mq) >> 16;
        int cnt = 0;
        #pragma unroll
        for (int r2=0;r2<4;r2++){
          uint32_t a2 = (cq >> (4*r2)) & 15u, b2 = (ck >> (4*r2)) & 15u;
          cnt += (int)((b2 == a2) | (b2 == ((a2 + 15u) & 15u)));
        }
        float rc = (cnt<=1) ? 1.0f : (cnt==2 ? 0.5f : (cnt==3 ? 0.3333333333f : 0.25f));
        float e = kill ? 0.0f : __expf(x - 0.10f) * rc;  // M0 = 0.10 > any valid logit
        uint16_t eu = f2b(e);
        rsp[reg] += bflo(eu);                            // sum the bf16-rounded weight
        Ps[(16*w + quad*4 + reg)*40 + nj*16 + l16] = eu;
      }
    }
    __syncthreads();
    // ---- P x V: O[16 x 128] += P[16 x 32] * V[32 x 128] ----
    short8 pa = *(const short8*)(Ps + (16*w + l16)*40 + quad*8);
    #pragma unroll
    for (int nd=0;nd<8;nd++){
      short8 vb = *(const short8*)(VT + (nd*16 + l16)*40 + quad*8);
      O[nd] = __builtin_amdgcn_mfma_f32_16x16x32_bf16(pa, vb, O[nd], 0, 0, 0);
    }
  }
  // ---- row sums: reduce across the 16 column-lanes ----
  #pragma unroll
  for (int off=1; off<16; off<<=1)
    #pragma unroll
    for (int reg=0;reg<4;reg++) rsp[reg] += __shfl_xor(rsp[reg], off);
  if (l16 == 0){
    #pragma unroll
    for (int reg=0;reg<4;reg++)
      rowsum[sbase + qs0 + 16*w + quad*4 + reg] = rsp[reg];
  }
  // ---- write O (bf16) via Qs bounce for coalesced 16B stores ----
  __syncthreads();
  #pragma unroll
  for (int nd=0;nd<8;nd++)
    #pragma unroll
    for (int reg=0;reg<4;reg++)
      Qs[(16*w + quad*4 + reg)*136 + nd*16 + l16] = f2b(O[nd][reg]);
  __syncthreads();
  #pragma unroll
  for (int i=0;i<4;i++){
    int ch = t + i*512;
    int row = ch >> 4, c16 = ch & 15;
    uint4 u = *(const uint4*)(Qs + row*136 + c16*8);
    *(uint4*)(attb + ((size_t)(sbase + qs0 + row))*DK + c16*8) = u;
  }
}

// ---------------- kernel 4: gather rounds to original order, normalize ----------------
__global__ __launch_bounds__(128) void k_out(const uint16_t* __restrict__ attb,
    const float* __restrict__ rowsum, const int* __restrict__ posA,
    float* __restrict__ out)
{
  int bid = blockIdx.x;               // b*LEN + l
  int b = bid >> 11, l = bid & (LEN-1);
  int t = threadIdx.x;
  float num = 0.f, den = 0.f;
  #pragma unroll
  for (int r=0;r<4;r++){
    int sp = posA[(size_t)(b*RND+r)*LEN + l];
    size_t ro = ((size_t)(b*RND+r)*LEN + sp);
    num += bflo((uint32_t)attb[ro*DK + t]);
    den += rowsum[ro];
  }
  out[(size_t)bid*DK + t] = num / den;
}

extern "C" void kernel_launch(void* const* d_in, const int* in_sizes, int n_in,
                              void* d_out, int out_size, void* d_ws, size_t ws_size,
                              hipStream_t stream)
{
  const float* q  = (const float*)d_in[0];
  const float* v  = (const float*)d_in[1];
  const float* rm = (const float*)d_in[3];
  float* out = (float*)d_out;

  char* w = (char*)d_ws;
  uint16_t* fqb = (uint16_t*)w;                                   // 8 MiB normalized q, bf16
  uint16_t* vbb = (uint16_t*)(w + (size_t)(8<<20));               // 8 MiB value, bf16
  uint8_t*  hsh = (uint8_t*)(w + (size_t)(16<<20));               // 128 KiB
  int* posA = (int*)(w + (size_t)(16<<20) + (1<<17));             // [BH][R][LEN]
  int* tokA = posA + BH*RND*LEN;
  int* meta = tokA + BH*RND*LEN;
  float* invn   = (float*)(meta + BH*RND*LEN);                    // 4 KiB
  float* rowsum = invn + BH*64;                                   // 512 KiB
  uint16_t* attb = (uint16_t*)(rowsum + BH*RND*LEN);              // 32 MiB bf16

  k_rmn  <<<dim3(BH),             dim3(64),  0, stream>>>(rm, invn);
  k_hash <<<dim3(BH*LEN),         dim3(64),  0, stream>>>(q, v, rm, invn, fqb, vbb, hsh);
  k_sort <<<dim3(BH*RND),         dim3(256), 0, stream>>>(hsh, posA, tokA);
  k_meta <<<dim3(BH*RND*LEN/256), dim3(256), 0, stream>>>(hsh, posA, tokA, meta);
  k_fattn<<<dim3(BH*RND*NB2),     dim3(512), 0, stream>>>(fqb, vbb, meta, attb, rowsum);
  k_out  <<<dim3(BH*LEN),         dim3(128), 0, stream>>>(attb, rowsum, posA, out);
}

// Round 5
// 199.739 us; speedup vs baseline: 3.9064x; 1.1940x over previous
//
#include <hip/hip_runtime.h>
#include <hip/hip_bf16.h>
#include <stdint.h>

constexpr int BH  = 16;    // batch*head
constexpr int LEN = 2048;
constexpr int DK  = 128;
constexpr int RND = 4;
constexpr int NB2 = 16;    // n_buckets/2 (chunk count)
constexpr int BL2 = 128;   // queries per chunk

typedef __attribute__((ext_vector_type(8))) short short8;
typedef __attribute__((ext_vector_type(4))) float f32x4;

__device__ __forceinline__ float bflo(uint32_t u){ return __uint_as_float(u << 16); }
__device__ __forceinline__ uint16_t f2b(float x){
  uint32_t u = __float_as_uint(x);
  return (uint16_t)((u + 0x7fffu + ((u >> 16) & 1u)) >> 16);   // RNE
}
__device__ __forceinline__ uint32_t pk2(float a, float b){
  return (uint32_t)f2b(a) | ((uint32_t)f2b(b) << 16);
}

// ---------------- kernel 1: 64 tokens/block; rm staged once in LDS ----------------
__global__ __launch_bounds__(256) void k_hash(const float* __restrict__ q,
    const float* __restrict__ v, const float* __restrict__ rm,
    uint16_t* __restrict__ fqb, uint16_t* __restrict__ vbb,
    uint8_t* __restrict__ hsh)
{
  __shared__ float rml[128*64];     // 32 KB
  __shared__ float invn_s[64];
  int b = blockIdx.x >> 5, chunk = blockIdx.x & 31;
  int t = threadIdx.x;
  const float* rmb = rm + (size_t)b*(128*64);
  #pragma unroll
  for (int i=0;i<8;i++){
    int lin = i*256 + t;
    int d = lin >> 4, c4 = lin & 15;
    float4 w = ((const float4*)rmb)[lin];
    *(float4*)(rml + d*64 + ((c4*4 + 8*(d>>5)) & 63)) = w;   // rotation is 4-aligned, no wrap
  }
  __syncthreads();
  if (t < 64){                       // rm column inverse norms
    float s2 = 0.f;
    for (int d=0; d<128; d++){
      float w = rml[d*64 + ((t + 8*(d>>5)) & 63)];
      s2 += w*w;
    }
    invn_s[t] = 1.0f / sqrtf(s2);
  }
  int tl = t >> 2, qq = t & 3;       // 4 threads per token, 32-d slice each
  int tok = chunk*64 + tl;
  size_t ro = ((size_t)b*LEN + tok)*DK;
  float qs[32];
  float ss = 0.f;
  #pragma unroll
  for (int i=0;i<8;i++){
    float4 w = *(const float4*)(q + ro + qq*32 + i*4);
    qs[i*4]=w.x; qs[i*4+1]=w.y; qs[i*4+2]=w.z; qs[i*4+3]=w.w;
    ss += w.x*w.x + w.y*w.y + w.z*w.z + w.w*w.w;
  }
  ss += __shfl_xor(ss,1); ss += __shfl_xor(ss,2);
  float rn = 1.0f / sqrtf(ss);
  #pragma unroll
  for (int i=0;i<32;i++) qs[i] *= rn;
  #pragma unroll
  for (int i=0;i<4;i++){
    uint4 u;
    u.x = pk2(qs[i*8+0], qs[i*8+1]); u.y = pk2(qs[i*8+2], qs[i*8+3]);
    u.z = pk2(qs[i*8+4], qs[i*8+5]); u.w = pk2(qs[i*8+6], qs[i*8+7]);
    *(uint4*)(fqb + ro + qq*32 + i*8) = u;
  }
  #pragma unroll
  for (int i=0;i<4;i++){
    float4 a = *(const float4*)(v + ro + qq*32 + i*8);
    float4 c = *(const float4*)(v + ro + qq*32 + i*8 + 4);
    uint4 u;
    u.x = pk2(a.x,a.y); u.y = pk2(a.z,a.w); u.z = pk2(c.x,c.y); u.w = pk2(c.z,c.w);
    *(uint4*)(vbb + ro + qq*32 + i*8) = u;
  }
  __syncthreads();
  uint8_t mybuck = 0;
  #pragma unroll
  for (int r=0;r<4;r++){
    float bp = -1e30f, bn = -1e30f; int bip = 0, bin = 16;
    for (int k4=0;k4<4;k4++){
      f32x4 acc = {0.f,0.f,0.f,0.f};
      int col = (r*16 + k4*4 + 8*qq) & 63;
      #pragma unroll 8
      for (int dd=0; dd<32; dd++){
        float4 w = *(const float4*)(rml + (qq*32+dd)*64 + col);
        float qv = qs[dd];
        acc[0] += qv*w.x; acc[1] += qv*w.y; acc[2] += qv*w.z; acc[3] += qv*w.w;
      }
      #pragma unroll
      for (int j=0;j<4;j++){
        float dj = acc[j];
        dj += __shfl_xor(dj,1); dj += __shfl_xor(dj,2);
        float hv = dj * invn_s[r*16 + k4*4 + j];
        int k = k4*4 + j;
        if ( hv > bp){ bp =  hv; bip = k; }
        if (-hv > bn){ bn = -hv; bin = k + 16; }
      }
    }
    if (qq == r) mybuck = (uint8_t)((bn > bp) ? bin : bip);
  }
  hsh[((size_t)(b*RND + qq))*LEN + tok] = mybuck;   // thread qq writes round qq
}

// ---------------- kernel 2: stable counting sort per (b,r) ----------------
__global__ __launch_bounds__(256) void k_sort(const uint8_t* __restrict__ hsh,
    int* __restrict__ posA, int* __restrict__ tokA)
{
  __shared__ int hist[32*256];
  __shared__ int sums[256];
  int br = blockIdx.x;
  int t = threadIdx.x;
  const uint8_t* hh = hsh + (size_t)br*LEN;
  uint8_t ub[8];
  #pragma unroll
  for (int i=0;i<8;i++) ub[i] = hh[t*8+i];
  #pragma unroll
  for (int k=0;k<32;k++) hist[k*256+t] = 0;
  __syncthreads();
  #pragma unroll
  for (int i=0;i<8;i++) hist[(int)ub[i]*256 + t] += 1;
  __syncthreads();
  int base = t*32, s0 = 0;
  for (int e=0;e<32;e++) s0 += hist[base+e];
  sums[t] = s0;
  __syncthreads();
  if (t == 0){
    int run = 0;
    for (int i=0;i<256;i++){ int tmp = sums[i]; sums[i] = run; run += tmp; }
  }
  __syncthreads();
  int run = sums[t];
  for (int e=0;e<32;e++){ int tmp = hist[base+e]; hist[base+e] = run; run += tmp; }
  __syncthreads();
  #pragma unroll
  for (int i=0;i<8;i++){
    int l = t*8+i, k = ub[i];
    int p = hist[k*256+t]++;
    posA[(size_t)br*LEN + l] = p;
    tokA[(size_t)br*LEN + p] = l;
  }
}

// ---------------- kernel 2b: pack meta = tok | bucket<<11 | chunkcode<<16 ----------------
__global__ __launch_bounds__(256) void k_meta(const uint8_t* __restrict__ hsh,
    const int* __restrict__ posA, const int* __restrict__ tokA, int* __restrict__ meta)
{
  int idx = blockIdx.x*256 + threadIdx.x;
  int br = idx >> 11;
  int b = br >> 2;
  int tok = tokA[idx];
  int bucket = hsh[(size_t)br*LEN + tok];
  int code = 0;
  #pragma unroll
  for (int r2=0;r2<4;r2++){
    int p = posA[(size_t)(b*4+r2)*LEN + tok];
    code |= (p >> 7) << (4*r2);
  }
  meta[idx] = tok | (bucket<<11) | (code<<16);
}

// ---------------- kernel 2c: gather V into sorted order, transposed [d][pos] ----------------
__global__ __launch_bounds__(256) void k_gath(const uint16_t* __restrict__ vbb,
    const int* __restrict__ tokA, uint16_t* __restrict__ vt_g)
{
  __shared__ uint16_t Vs[128*128];   // 32 KB, [pos][d] granule-swizzled
  __shared__ int tk_s[128];
  int bid = blockIdx.x;
  int chunk = bid & 15, br = bid >> 4;
  int b = br >> 2;
  int t = threadIdx.x;
  int pos0 = chunk*128;
  if (t < 128) tk_s[t] = tokA[(size_t)br*LEN + pos0 + t];
  __syncthreads();
  {
    int pos = t >> 1, hf = t & 1;
    int tok = tk_s[pos];
    const uint4* src = (const uint4*)(vbb + ((size_t)b*LEN + tok)*DK) + hf*8;
    #pragma unroll
    for (int i=0;i<8;i++){
      int g = hf*8 + i;
      uint4 u = src[i];
      *(uint4*)(Vs + pos*128 + ((g ^ (pos & 15))*8)) = u;
    }
  }
  __syncthreads();
  {
    int d = t >> 1, ph = (t & 1)*64;
    int g = d >> 3, dl = d & 7;
    uint16_t* dst = vt_g + ((size_t)br*DK + d)*LEN + pos0 + ph;
    #pragma unroll
    for (int pgi=0; pgi<8; pgi++){
      uint16_t tmp[8];
      #pragma unroll
      for (int j=0;j<8;j++){
        int pos = ph + pgi*8 + j;
        tmp[j] = Vs[pos*128 + ((g ^ (pos & 15))*8) + dl];
      }
      *(uint4*)(dst + pgi*8) = *(uint4*)tmp;
    }
  }
}

// ---------------- kernel 3: fused MFMA attention (S^T form, Q in registers) ----------------
__global__ __launch_bounds__(512, 4) void k_fattn(
    const uint16_t* __restrict__ fqb, const uint16_t* __restrict__ vt_g,
    const int* __restrict__ meta, uint16_t* __restrict__ attb,
    float* __restrict__ rowsum)
{
  __shared__ __align__(16) char smem[30208];
  uint16_t* Ks  = (uint16_t*)smem;               // 32*136*2  = 8704
  uint16_t* VT  = (uint16_t*)(smem + 8704);      // 128*40*2  = 10240
  uint16_t* Ps  = (uint16_t*)(smem + 18944);     // 128*40*2  = 10240
  int*      km_s= (int*)(smem + 29184);          // 256*4     = 1024
  uint16_t* Qb  = (uint16_t*)smem;               // alias for epilogue: 64*136*2 = 17408

  int bid = blockIdx.x;
  int n = bid & 15, r = (bid>>4)&3, b = bid>>6;
  int t = threadIdx.x;
  int w = t >> 6, lane = t & 63, l16 = lane & 15, quad = lane >> 4;
  int br = b*RND + r;
  int sbase = br*LEN, qs0 = n*BL2;
  size_t gbase = (size_t)b*LEN;

  if (t < 256){
    int jg = t;
    int sk = (jg < BL2) ? (((n+NB2-1)&(NB2-1))*BL2 + jg) : (n*BL2 + jg - BL2);
    km_s[t] = meta[sbase + sk];
  }
  int mq = meta[sbase + qs0 + 16*w + l16];     // this lane's q (one per lane)
  int qtok = mq & 2047;
  int tq = qtok;
  uint32_t cq = ((uint32_t)mq) >> 16;
  short8 qf[4];                                 // Q fragment in registers (B operand)
  const uint16_t* qrow = fqb + (gbase + qtok)*DK + quad*8;
  #pragma unroll
  for (int dc=0;dc<4;dc++) qf[dc] = *(const short8*)(qrow + dc*32);

  f32x4 O[8];
  #pragma unroll
  for (int i=0;i<8;i++) O[i] = (f32x4){0.f,0.f,0.f,0.f};
  float rsp = 0.f;
  const uint16_t* vtb = vt_g + (size_t)br*DK*LEN;

  for (int c=0;c<8;c++){
    __syncthreads();
    int wpos = (c<4) ? (((n+NB2-1)&(NB2-1))*BL2 + c*32) : (n*BL2 + (c-4)*32);
    { // stage K (32 keys x 128 d), vector writes
      int row = t >> 4, c16 = t & 15;
      int tok = km_s[c*32 + row] & 2047;
      uint4 u = *(const uint4*)(fqb + (gbase + tok)*DK + c16*8);
      *(uint4*)(Ks + row*136 + c16*8) = u;
    }
    { // stage VT (128 d x 32 keys) from pre-transposed global, vector writes
      int d = t >> 2, kg = t & 3;
      uint4 u = *(const uint4*)(vtb + (size_t)d*LEN + wpos + kg*8);
      *(uint4*)(VT + d*40 + kg*8) = u;
    }
    __syncthreads();
    // ---- S^T = K * Q^T: A = K rows (LDS), B = Q rows (registers) ----
    f32x4 S0 = {0.f,0.f,0.f,0.f}, S1 = {0.f,0.f,0.f,0.f};
    #pragma unroll
    for (int dc=0;dc<4;dc++){
      short8 a0 = *(const short8*)(Ks + l16*136      + dc*32 + quad*8);
      short8 a1 = *(const short8*)(Ks + (16+l16)*136 + dc*32 + quad*8);
      S0 = __builtin_amdgcn_mfma_f32_16x16x32_bf16(a0, qf[dc], S0, 0, 0, 0);
      S1 = __builtin_amdgcn_mfma_f32_16x16x32_bf16(a1, qf[dc], S1, 0, 0, 0);
    }
    // ---- epilogue: lane owns q = 16w+l16, keys quad*4+reg (+16) ----
    #pragma unroll
    for (int nj=0;nj<2;nj++){
      f32x4 S = nj ? S1 : S0;
      uint16_t eb[4];
      #pragma unroll
      for (int reg=0;reg<4;reg++){
        int km = km_s[c*32 + nj*16 + quad*4 + reg];
        int tk = km & 2047;
        uint32_t ck = ((uint32_t)km) >> 16;
        uint32_t ckp1 = ((ck & 0x7777u) + 0x1111u) ^ (ck & 0x8888u);  // nibble-wise +1 mod 16
        uint32_t x1 = cq ^ ck, x2 = cq ^ ckp1;
        // borrow-free per-nibble zero detect: bit3 set iff nibble == 0
        uint32_t h1 = ~(((x1 & 0x7777u) + 0x7777u) | x1) & 0x8888u;
        uint32_t h2 = ~(((x2 & 0x7777u) + 0x7777u) | x2) & 0x8888u;
        uint32_t msum = (h1 >> 3) + (h2 >> 3);
        uint32_t cnt = ((msum * 0x1111u) >> 12) & 15u;                // dup count 1..4
        float rcf = __builtin_amdgcn_rcpf((float)cnt);
        float t1 = fmaf(S[reg], 0.08838834764831845f, -0.1f);        // scale, fixed max M0=0.1
        t1 = (tq == tk) ? -30.1f : t1;                                // self
        bool kill = ((((uint32_t)(mq ^ km)) & 0xF800u) != 0u) || (tq < tk);
        t1 = kill ? -1e9f : t1;
        float e = __expf(t1) * rcf;
        eb[reg] = f2b(e);
        rsp += bflo(eb[reg]);                  // sum the bf16-rounded weight PV uses
      }
      uint32_t* pdst = (uint32_t*)(Ps + (16*w + l16)*40 + nj*16 + quad*4);
      pdst[0] = (uint32_t)eb[0] | ((uint32_t)eb[1] << 16);
      pdst[1] = (uint32_t)eb[2] | ((uint32_t)eb[3] << 16);
    }
    __syncthreads();
    // ---- O += P * V ----
    short8 pa = *(const short8*)(Ps + (16*w + l16)*40 + quad*8);
    #pragma unroll
    for (int nd=0;nd<8;nd++){
      short8 vb = *(const short8*)(VT + (nd*16 + l16)*40 + quad*8);
      O[nd] = __builtin_amdgcn_mfma_f32_16x16x32_bf16(pa, vb, O[nd], 0, 0, 0);
    }
  }
  rsp += __shfl_xor(rsp, 16);
  rsp += __shfl_xor(rsp, 32);
  if (lane < 16) rowsum[sbase + qs0 + 16*w + l16] = rsp;
  // ---- output via LDS bounce (2 half-passes), coalesced 16B stores ----
  #pragma unroll
  for (int p=0;p<2;p++){
    __syncthreads();
    if ((w>>2) == p){
      #pragma unroll
      for (int nd=0;nd<8;nd++)
        #pragma unroll
        for (int reg=0;reg<4;reg++)
          Qb[(16*(w&3) + quad*4 + reg)*136 + nd*16 + l16] = f2b(O[nd][reg]);
    }
    __syncthreads();
    #pragma unroll
    for (int i=0;i<2;i++){
      int ch = t + i*512;
      int row = ch >> 4, c16 = ch & 15;
      uint4 u = *(const uint4*)(Qb + row*136 + c16*8);
      *(uint4*)(attb + ((size_t)(sbase + qs0 + p*64 + row))*DK + c16*8) = u;
    }
  }
}

// ---------------- kernel 4: gather rounds to original order, normalize ----------------
__global__ __launch_bounds__(256) void k_out(const uint16_t* __restrict__ attb,
    const float* __restrict__ rowsum, const int* __restrict__ posA,
    float* __restrict__ out)
{
  int idx = blockIdx.x*2 + (threadIdx.x >> 7);   // b*LEN + l
  int tt = threadIdx.x & 127;
  int b = idx >> 11;
  int l = idx & (LEN-1);
  float num = 0.f, den = 0.f;
  #pragma unroll
  for (int r=0;r<4;r++){
    int sp = posA[(size_t)(b*RND+r)*LEN + l];
    size_t ro = ((size_t)(b*RND+r)*LEN + sp);
    num += bflo((uint32_t)attb[ro*DK + tt]);
    den += rowsum[ro];
  }
  out[(size_t)idx*DK + tt] = num / den;
}

extern "C" void kernel_launch(void* const* d_in, const int* in_sizes, int n_in,
                              void* d_out, int out_size, void* d_ws, size_t ws_size,
                              hipStream_t stream)
{
  const float* q  = (const float*)d_in[0];
  const float* v  = (const float*)d_in[1];
  const float* rm = (const float*)d_in[3];
  float* out = (float*)d_out;

  char* w = (char*)d_ws;
  uint16_t* fqb    = (uint16_t*)(w + 0);               // 8 MiB normalized q, bf16
  uint8_t*  hsh    = (uint8_t*) (w + 8388608);         // 128 KiB
  int*      posA   = (int*)     (w + 8519680);         // 512 KiB
  int*      tokA   = (int*)     (w + 9043968);         // 512 KiB
  int*      meta   = (int*)     (w + 9568256);         // 512 KiB
  float*    rowsum = (float*)   (w + 10092544);        // 512 KiB
  uint16_t* vt_g   = (uint16_t*)(w + 10616832);        // 32 MiB sorted V^T, bf16
  uint16_t* attb   = (uint16_t*)(w + 44171264);        // 32 MiB unnormalized O, bf16
  uint16_t* vbb    = attb;  // vbb (bf16 V copy) is dead before k_fattn writes attb

  k_hash <<<dim3(BH*32),          dim3(256), 0, stream>>>(q, v, rm, fqb, vbb, hsh);
  k_sort <<<dim3(BH*RND),         dim3(256), 0, stream>>>(hsh, posA, tokA);
  k_meta <<<dim3(BH*RND*LEN/256), dim3(256), 0, stream>>>(hsh, posA, tokA, meta);
  k_gath <<<dim3(BH*RND*NB2),     dim3(256), 0, stream>>>(vbb, tokA, vt_g);
  k_fattn<<<dim3(BH*RND*NB2),     dim3(512), 0, stream>>>(fqb, vt_g, meta, attb, rowsum);
  k_out  <<<dim3(BH*LEN/2),       dim3(256), 0, stream>>>(attb, rowsum, posA, out);
}

// Round 6
// 182.126 us; speedup vs baseline: 4.2842x; 1.0967x over previous
//
#include <hip/hip_runtime.h>
#include <hip/hip_bf16.h>
#include <stdint.h>

constexpr int BH  = 16;    // batch*head
constexpr int LEN = 2048;
constexpr int DK  = 128;
constexpr int RND = 4;
constexpr int NB2 = 16;    // n_buckets/2 (chunk count)
constexpr int BL2 = 128;   // queries per chunk

typedef __attribute__((ext_vector_type(8))) short short8;
typedef __attribute__((ext_vector_type(4))) float f32x4;

__device__ __forceinline__ float bflo(uint32_t u){ return __uint_as_float(u << 16); }
__device__ __forceinline__ uint16_t f2b(float x){
  uint32_t u = __float_as_uint(x);
  return (uint16_t)((u + 0x7fffu + ((u >> 16) & 1u)) >> 16);   // RNE
}
__device__ __forceinline__ uint32_t pk2(float a, float b){
  return (uint32_t)f2b(a) | ((uint32_t)f2b(b) << 16);
}

// ---------------- kernel 1: 64 tokens/block; rm staged once in LDS ----------------
__global__ __launch_bounds__(256) void k_hash(const float* __restrict__ q,
    const float* __restrict__ v, const float* __restrict__ rm,
    uint16_t* __restrict__ fqb, uint16_t* __restrict__ vbb,
    uint8_t* __restrict__ hsh)
{
  __shared__ float rml[128*64];     // 32 KB
  __shared__ float invn_s[64];
  int b = blockIdx.x >> 5, chunk = blockIdx.x & 31;
  int t = threadIdx.x;
  const float* rmb = rm + (size_t)b*(128*64);
  #pragma unroll
  for (int i=0;i<8;i++){
    int lin = i*256 + t;
    int d = lin >> 4, c4 = lin & 15;
    float4 w = ((const float4*)rmb)[lin];
    *(float4*)(rml + d*64 + ((c4*4 + 8*(d>>5)) & 63)) = w;   // rotation is 4-aligned, no wrap
  }
  __syncthreads();
  if (t < 64){                       // rm column inverse norms
    float s2 = 0.f;
    for (int d=0; d<128; d++){
      float w = rml[d*64 + ((t + 8*(d>>5)) & 63)];
      s2 += w*w;
    }
    invn_s[t] = 1.0f / sqrtf(s2);
  }
  int tl = t >> 2, qq = t & 3;       // 4 threads per token, 32-d slice each
  int tok = chunk*64 + tl;
  size_t ro = ((size_t)b*LEN + tok)*DK;
  float qs[32];
  float ss = 0.f;
  #pragma unroll
  for (int i=0;i<8;i++){
    float4 w = *(const float4*)(q + ro + qq*32 + i*4);
    qs[i*4]=w.x; qs[i*4+1]=w.y; qs[i*4+2]=w.z; qs[i*4+3]=w.w;
    ss += w.x*w.x + w.y*w.y + w.z*w.z + w.w*w.w;
  }
  ss += __shfl_xor(ss,1); ss += __shfl_xor(ss,2);
  float rn = 1.0f / sqrtf(ss);
  #pragma unroll
  for (int i=0;i<32;i++) qs[i] *= rn;
  #pragma unroll
  for (int i=0;i<4;i++){
    uint4 u;
    u.x = pk2(qs[i*8+0], qs[i*8+1]); u.y = pk2(qs[i*8+2], qs[i*8+3]);
    u.z = pk2(qs[i*8+4], qs[i*8+5]); u.w = pk2(qs[i*8+6], qs[i*8+7]);
    *(uint4*)(fqb + ro + qq*32 + i*8) = u;
  }
  #pragma unroll
  for (int i=0;i<4;i++){
    float4 a = *(const float4*)(v + ro + qq*32 + i*8);
    float4 c = *(const float4*)(v + ro + qq*32 + i*8 + 4);
    uint4 u;
    u.x = pk2(a.x,a.y); u.y = pk2(a.z,a.w); u.z = pk2(c.x,c.y); u.w = pk2(c.z,c.w);
    *(uint4*)(vbb + ro + qq*32 + i*8) = u;
  }
  __syncthreads();
  uint8_t mybuck = 0;
  #pragma unroll
  for (int r=0;r<4;r++){
    float bp = -1e30f, bn = -1e30f; int bip = 0, bin = 16;
    for (int k4=0;k4<4;k4++){
      f32x4 acc = {0.f,0.f,0.f,0.f};
      int col = (r*16 + k4*4 + 8*qq) & 63;
      #pragma unroll 8
      for (int dd=0; dd<32; dd++){
        float4 w = *(const float4*)(rml + (qq*32+dd)*64 + col);
        float qv = qs[dd];
        acc[0] += qv*w.x; acc[1] += qv*w.y; acc[2] += qv*w.z; acc[3] += qv*w.w;
      }
      #pragma unroll
      for (int j=0;j<4;j++){
        float dj = acc[j];
        dj += __shfl_xor(dj,1); dj += __shfl_xor(dj,2);
        float hv = dj * invn_s[r*16 + k4*4 + j];
        int k = k4*4 + j;
        if ( hv > bp){ bp =  hv; bip = k; }
        if (-hv > bn){ bn = -hv; bin = k + 16; }
      }
    }
    if (qq == r) mybuck = (uint8_t)((bn > bp) ? bin : bip);
  }
  hsh[((size_t)(b*RND + qq))*LEN + tok] = mybuck;   // thread qq writes round qq
}

// ---------------- kernel 2: stable counting sort per (b,r) ----------------
// tokA entries now carry the bucket in bits 11..15 (saves k_meta's hsh gather).
__global__ __launch_bounds__(256) void k_sort(const uint8_t* __restrict__ hsh,
    int* __restrict__ posA, int* __restrict__ tokA)
{
  __shared__ int hist[32*256];
  __shared__ int sums[256];
  int br = blockIdx.x;
  int t = threadIdx.x;
  const uint8_t* hh = hsh + (size_t)br*LEN;
  uint8_t ub[8];
  #pragma unroll
  for (int i=0;i<8;i++) ub[i] = hh[t*8+i];
  #pragma unroll
  for (int k=0;k<32;k++) hist[k*256+t] = 0;
  __syncthreads();
  #pragma unroll
  for (int i=0;i<8;i++) hist[(int)ub[i]*256 + t] += 1;
  __syncthreads();
  int base = t*32, s0 = 0;
  for (int e=0;e<32;e++) s0 += hist[base+e];
  sums[t] = s0;
  __syncthreads();
  if (t == 0){
    int run = 0;
    for (int i=0;i<256;i++){ int tmp = sums[i]; sums[i] = run; run += tmp; }
  }
  __syncthreads();
  int run = sums[t];
  for (int e=0;e<32;e++){ int tmp = hist[base+e]; hist[base+e] = run; run += tmp; }
  __syncthreads();
  #pragma unroll
  for (int i=0;i<8;i++){
    int l = t*8+i, k = ub[i];
    int p = hist[k*256+t]++;
    posA[(size_t)br*LEN + l] = p;
    tokA[(size_t)br*LEN + p] = l | (k << 11);
  }
}

// ---------------- kernel 2b: pack meta = tok | bucket<<11 | chunkcode<<16 ----------------
__global__ __launch_bounds__(256) void k_meta(
    const int* __restrict__ posA, const int* __restrict__ tokA, int* __restrict__ meta)
{
  int idx = blockIdx.x*256 + threadIdx.x;
  int br = idx >> 11;
  int b = br >> 2;
  int raw = tokA[idx];
  int tok = raw & 2047;
  int code = 0;
  #pragma unroll
  for (int r2=0;r2<4;r2++){
    int p = posA[(size_t)(b*4+r2)*LEN + tok];
    code |= (p >> 7) << (4*r2);
  }
  meta[idx] = raw | (code<<16);    // raw already = tok | bucket<<11
}

// ---------------- kernel 3: fused MFMA attention ----------------
// S^T form (Q in registers), in-LDS V transpose, 2 barriers per K-slice
// via one-stage pipeline: [QK + VT-transpose + epilogue] | [PV(c) + stage(c+1)].
__global__ __launch_bounds__(512, 4) void k_fattn(
    const uint16_t* __restrict__ fqb, const uint16_t* __restrict__ vbb,
    const int* __restrict__ meta, uint16_t* __restrict__ attb,
    float* __restrict__ rowsum)
{
  __shared__ __align__(16) char smem[39424];
  uint16_t* Ks  = (uint16_t*)smem;               // 32*136*2 = 8704
  uint16_t* Vs2 = (uint16_t*)(smem + 8704);      // 32*128*2 = 8192 (granule-swizzled raw V)
  uint16_t* VT  = (uint16_t*)(smem + 16896);     // 128*40*2 = 10240 (V transposed [d][key])
  uint16_t* Ps  = (uint16_t*)(smem + 27136);     // 128*40*2 = 10240
  uint2*    km2 = (uint2*)(smem + 37376);        // 256*8    = 2048  (.x=km16, .y=ck|ckp1<<16)
  uint16_t* Qb  = (uint16_t*)smem;               // epilogue alias: 64*136*2 = 17408

  int bid = blockIdx.x;
  int n = bid & 15, r = (bid>>4)&3, b = bid>>6;
  int t = threadIdx.x;
  int w = t >> 6, lane = t & 63, l16 = lane & 15, quad = lane >> 4;
  int br = b*RND + r;
  int sbase = br*LEN, qs0 = n*BL2;
  size_t gbase = (size_t)b*LEN;

  if (t < 256){
    int sk = (t < BL2) ? (((n+NB2-1)&15)*BL2 + t) : (n*BL2 + t - BL2);
    int km = meta[sbase + sk];
    uint32_t ck = ((uint32_t)km) >> 16;
    uint32_t ckp1 = ((ck & 0x7777u) + 0x1111u) ^ (ck & 0x8888u);  // nibble +1 mod 16
    uint2 kv; kv.x = (uint32_t)(km & 0xFFFF); kv.y = ck | (ckp1 << 16);
    km2[t] = kv;
  }
  int mq = meta[sbase + qs0 + 16*w + l16];     // this lane's q
  uint32_t mq16 = (uint32_t)(mq & 0xFFFF);
  uint32_t cq = ((uint32_t)mq) >> 16;
  short8 qf[4];                                 // Q fragment (B operand)
  const uint16_t* qrow = fqb + (gbase + (mq & 2047))*DK + quad*8;
  #pragma unroll
  for (int dc=0;dc<4;dc++) qf[dc] = *(const short8*)(qrow + dc*32);

  f32x4 O[8];
  #pragma unroll
  for (int i=0;i<8;i++) O[i] = (f32x4){0.f,0.f,0.f,0.f};
  float rsp = 0.f;

  int srow = t >> 4, sg = t & 15;              // staging coords (32 rows x 16 granules)
  int swz = (sg ^ (srow & 15))*8;
  __syncthreads();                              // km2 visible
  { // stage slice 0
    int tok = (int)(km2[srow].x & 2047u);
    uint4 ku = *(const uint4*)(fqb + (gbase + tok)*DK + sg*8);
    uint4 vu = *(const uint4*)(vbb + (gbase + tok)*DK + sg*8);
    *(uint4*)(Ks  + srow*136 + sg*8) = ku;
    *(uint4*)(Vs2 + srow*128 + swz)  = vu;
  }

  for (int c=0;c<8;c++){
    __syncthreads();
    // ---- S^T = K * Q^T ----
    f32x4 S0 = {0.f,0.f,0.f,0.f}, S1 = {0.f,0.f,0.f,0.f};
    #pragma unroll
    for (int dc=0;dc<4;dc++){
      short8 a0 = *(const short8*)(Ks + l16*136      + dc*32 + quad*8);
      short8 a1 = *(const short8*)(Ks + (16+l16)*136 + dc*32 + quad*8);
      S0 = __builtin_amdgcn_mfma_f32_16x16x32_bf16(a0, qf[dc], S0, 0, 0, 0);
      S1 = __builtin_amdgcn_mfma_f32_16x16x32_bf16(a1, qf[dc], S1, 0, 0, 0);
    }
    // ---- VT transpose (needed only after next barrier, overlaps QK/epilogue) ----
    {
      int d = t >> 2, kg = t & 3, g = d >> 3, dl = d & 7;
      uint16_t tmp[8];
      #pragma unroll
      for (int j=0;j<8;j++){
        int key = kg*8 + j;
        tmp[j] = Vs2[key*128 + ((g ^ (key & 15))*8) + dl];
      }
      *(uint4*)(VT + d*40 + kg*8) = *(uint4*)tmp;
    }
    // ---- epilogue: lane owns q = 16w+l16, keys quad*4+reg (+16) ----
    #pragma unroll
    for (int nj=0;nj<2;nj++){
      uint32_t uu[4];
      #pragma unroll
      for (int reg=0;reg<4;reg++){
        uint2 kv = km2[c*32 + nj*16 + quad*4 + reg];
        uint32_t km16 = kv.x;
        uint32_t ck   = kv.y & 0xFFFFu;
        uint32_t ckp1 = kv.y >> 16;
        uint32_t xr = mq16 ^ km16;
        uint32_t x1 = cq ^ ck, x2 = cq ^ ckp1;
        uint32_t h1 = ~(((x1 & 0x7777u) + 0x7777u) | x1) & 0x8888u;
        uint32_t h2 = ~(((x2 & 0x7777u) + 0x7777u) | x2) & 0x8888u;
        uint32_t msum = (h1 >> 3) + (h2 >> 3);
        uint32_t cnt = ((msum * 0x1111u) >> 12) & 15u;     // dup count 1..4
        float rcf = __builtin_amdgcn_rcpf((float)cnt);
        float S = (nj ? S1 : S0)[reg];
        // arg = (S/sqrt(128) - M0) * log2(e), M0 = 0.1
        float arg = fmaf(S, 0.12751743f, -0.14426950f);
        arg = (xr == 0u) ? -43.425121f : arg;               // self
        bool kill = (xr >= 2048u) | (mq16 < km16);
        arg = kill ? -1e9f : arg;                           // exp2 underflows to 0
        float e = __builtin_amdgcn_exp2f(arg) * rcf;
        rsp += e;
        uu[reg] = __float_as_uint(e);
      }
      uint32_t* pdst = (uint32_t*)(Ps + (16*w + l16)*40 + nj*16 + quad*4);
      pdst[0] = __builtin_amdgcn_perm(uu[1], uu[0], 0x07060302);  // truncate-pack bf16x2
      pdst[1] = __builtin_amdgcn_perm(uu[3], uu[2], 0x07060302);
    }
    __syncthreads();
    // ---- stage slice c+1 (global loads launch first, hide under PV) ----
    if (c < 7){
      int tok = (int)(km2[(c+1)*32 + srow].x & 2047u);
      uint4 ku = *(const uint4*)(fqb + (gbase + tok)*DK + sg*8);
      uint4 vu = *(const uint4*)(vbb + (gbase + tok)*DK + sg*8);
      *(uint4*)(Ks  + srow*136 + sg*8) = ku;
      *(uint4*)(Vs2 + srow*128 + swz)  = vu;
    }
    // ---- O += P * V ----
    short8 pa = *(const short8*)(Ps + (16*w + l16)*40 + quad*8);
    #pragma unroll
    for (int nd=0;nd<8;nd++){
      short8 vb = *(const short8*)(VT + (nd*16 + l16)*40 + quad*8);
      O[nd] = __builtin_amdgcn_mfma_f32_16x16x32_bf16(pa, vb, O[nd], 0, 0, 0);
    }
  }
  rsp += __shfl_xor(rsp, 16);
  rsp += __shfl_xor(rsp, 32);
  if (lane < 16) rowsum[sbase + qs0 + 16*w + l16] = rsp;
  // ---- output via LDS bounce (2 half-passes), coalesced 16B stores ----
  #pragma unroll
  for (int p=0;p<2;p++){
    __syncthreads();
    if ((w>>2) == p){
      #pragma unroll
      for (int nd=0;nd<8;nd++)
        #pragma unroll
        for (int reg=0;reg<4;reg++)
          Qb[(16*(w&3) + quad*4 + reg)*136 + nd*16 + l16] = f2b(O[nd][reg]);
    }
    __syncthreads();
    #pragma unroll
    for (int i=0;i<2;i++){
      int ch = t + i*512;
      int row = ch >> 4, c16 = ch & 15;
      uint4 u = *(const uint4*)(Qb + row*136 + c16*8);
      *(uint4*)(attb + ((size_t)(sbase + qs0 + p*64 + row))*DK + c16*8) = u;
    }
  }
}

// ---------------- kernel 4: gather rounds to original order, normalize ----------------
__global__ __launch_bounds__(256) void k_out(const uint16_t* __restrict__ attb,
    const float* __restrict__ rowsum, const int* __restrict__ posA,
    float* __restrict__ out)
{
  int idx = blockIdx.x*2 + (threadIdx.x >> 7);   // b*LEN + l
  int tt = threadIdx.x & 127;
  int b = idx >> 11;
  int l = idx & (LEN-1);
  float num = 0.f, den = 0.f;
  #pragma unroll
  for (int r=0;r<4;r++){
    int sp = posA[(size_t)(b*RND+r)*LEN + l];
    size_t ro = ((size_t)(b*RND+r)*LEN + sp);
    num += bflo((uint32_t)attb[ro*DK + tt]);
    den += rowsum[ro];
  }
  out[(size_t)idx*DK + tt] = num / den;
}

extern "C" void kernel_launch(void* const* d_in, const int* in_sizes, int n_in,
                              void* d_out, int out_size, void* d_ws, size_t ws_size,
                              hipStream_t stream)
{
  const float* q  = (const float*)d_in[0];
  const float* v  = (const float*)d_in[1];
  const float* rm = (const float*)d_in[3];
  float* out = (float*)d_out;

  char* w = (char*)d_ws;
  uint16_t* fqb    = (uint16_t*)(w + 0);               // 8 MiB normalized q, bf16
  uint16_t* vbb    = (uint16_t*)(w + 8388608);         // 8 MiB value, bf16
  uint8_t*  hsh    = (uint8_t*) (w + 16777216);        // 128 KiB
  int*      posA   = (int*)     (w + 16908288);        // 512 KiB
  int*      tokA   = (int*)     (w + 17432576);        // 512 KiB
  int*      meta   = (int*)     (w + 17956864);        // 512 KiB
  float*    rowsum = (float*)   (w + 18481152);        // 512 KiB
  uint16_t* attb   = (uint16_t*)(w + 19005440);        // 32 MiB unnormalized O, bf16

  k_hash <<<dim3(BH*32),          dim3(256), 0, stream>>>(q, v, rm, fqb, vbb, hsh);
  k_sort <<<dim3(BH*RND),         dim3(256), 0, stream>>>(hsh, posA, tokA);
  k_meta <<<dim3(BH*RND*LEN/256), dim3(256), 0, stream>>>(posA, tokA, meta);
  k_fattn<<<dim3(BH*RND*NB2),     dim3(512), 0, stream>>>(fqb, vbb, meta, attb, rowsum);
  k_out  <<<dim3(BH*LEN/2),       dim3(256), 0, stream>>>(attb, rowsum, posA, out);
}

// Round 7
// 173.309 us; speedup vs baseline: 4.5021x; 1.0509x over previous
//
#include <hip/hip_runtime.h>
#include <hip/hip_bf16.h>
#include <stdint.h>

constexpr int BH  = 16;    // batch*head
constexpr int LEN = 2048;
constexpr int DK  = 128;
constexpr int RND = 4;
constexpr int NB2 = 16;    // n_buckets/2 (chunk count)
constexpr int BL2 = 128;   // queries per chunk

typedef __attribute__((ext_vector_type(8)))  short short8;
typedef __attribute__((ext_vector_type(4)))  float f32x4;
typedef __attribute__((ext_vector_type(16))) float f32x16;

__device__ __forceinline__ float bflo(uint32_t u){ return __uint_as_float(u << 16); }
__device__ __forceinline__ uint16_t f2b(float x){
  uint32_t u = __float_as_uint(x);
  return (uint16_t)((u + 0x7fffu + ((u >> 16) & 1u)) >> 16);   // RNE
}
__device__ __forceinline__ uint32_t pk2(float a, float b){
  return (uint32_t)f2b(a) | ((uint32_t)f2b(b) << 16);
}

// ---------------- kernel 1: 64 tokens/block; rm staged once in LDS ----------------
__global__ __launch_bounds__(256) void k_hash(const float* __restrict__ q,
    const float* __restrict__ v, const float* __restrict__ rm,
    uint16_t* __restrict__ fqb, uint16_t* __restrict__ vbb,
    uint8_t* __restrict__ hsh)
{
  __shared__ float rml[128*64];     // 32 KB
  __shared__ float invn_s[64];
  int b = blockIdx.x >> 5, chunk = blockIdx.x & 31;
  int t = threadIdx.x;
  const float* rmb = rm + (size_t)b*(128*64);
  #pragma unroll
  for (int i=0;i<8;i++){
    int lin = i*256 + t;
    int d = lin >> 4, c4 = lin & 15;
    float4 w = ((const float4*)rmb)[lin];
    *(float4*)(rml + d*64 + ((c4*4 + 8*(d>>5)) & 63)) = w;   // rotation is 4-aligned, no wrap
  }
  __syncthreads();
  if (t < 64){                       // rm column inverse norms
    float s2 = 0.f;
    for (int d=0; d<128; d++){
      float w = rml[d*64 + ((t + 8*(d>>5)) & 63)];
      s2 += w*w;
    }
    invn_s[t] = 1.0f / sqrtf(s2);
  }
  int tl = t >> 2, qq = t & 3;       // 4 threads per token, 32-d slice each
  int tok = chunk*64 + tl;
  size_t ro = ((size_t)b*LEN + tok)*DK;
  float qs[32];
  float ss = 0.f;
  #pragma unroll
  for (int i=0;i<8;i++){
    float4 w = *(const float4*)(q + ro + qq*32 + i*4);
    qs[i*4]=w.x; qs[i*4+1]=w.y; qs[i*4+2]=w.z; qs[i*4+3]=w.w;
    ss += w.x*w.x + w.y*w.y + w.z*w.z + w.w*w.w;
  }
  ss += __shfl_xor(ss,1); ss += __shfl_xor(ss,2);
  float rn = 1.0f / sqrtf(ss);
  #pragma unroll
  for (int i=0;i<32;i++) qs[i] *= rn;
  #pragma unroll
  for (int i=0;i<4;i++){
    uint4 u;
    u.x = pk2(qs[i*8+0], qs[i*8+1]); u.y = pk2(qs[i*8+2], qs[i*8+3]);
    u.z = pk2(qs[i*8+4], qs[i*8+5]); u.w = pk2(qs[i*8+6], qs[i*8+7]);
    *(uint4*)(fqb + ro + qq*32 + i*8) = u;
  }
  #pragma unroll
  for (int i=0;i<4;i++){
    float4 a = *(const float4*)(v + ro + qq*32 + i*8);
    float4 c = *(const float4*)(v + ro + qq*32 + i*8 + 4);
    uint4 u;
    u.x = pk2(a.x,a.y); u.y = pk2(a.z,a.w); u.z = pk2(c.x,c.y); u.w = pk2(c.z,c.w);
    *(uint4*)(vbb + ro + qq*32 + i*8) = u;
  }
  __syncthreads();
  uint8_t mybuck = 0;
  #pragma unroll
  for (int r=0;r<4;r++){
    float bp = -1e30f, bn = -1e30f; int bip = 0, bin = 16;
    for (int k4=0;k4<4;k4++){
      f32x4 acc = {0.f,0.f,0.f,0.f};
      int col = (r*16 + k4*4 + 8*qq) & 63;
      #pragma unroll 8
      for (int dd=0; dd<32; dd++){
        float4 w = *(const float4*)(rml + (qq*32+dd)*64 + col);
        float qv = qs[dd];
        acc[0] += qv*w.x; acc[1] += qv*w.y; acc[2] += qv*w.z; acc[3] += qv*w.w;
      }
      #pragma unroll
      for (int j=0;j<4;j++){
        float dj = acc[j];
        dj += __shfl_xor(dj,1); dj += __shfl_xor(dj,2);
        float hv = dj * invn_s[r*16 + k4*4 + j];
        int k = k4*4 + j;
        if ( hv > bp){ bp =  hv; bip = k; }
        if (-hv > bn){ bn = -hv; bin = k + 16; }
      }
    }
    if (qq == r) mybuck = (uint8_t)((bn > bp) ? bin : bip);
  }
  hsh[((size_t)(b*RND + qq))*LEN + tok] = mybuck;   // thread qq writes round qq
}

// ---------------- kernel 2: stable counting sort per (b,r), parallel scan ----------------
__global__ __launch_bounds__(256) void k_sort(const uint8_t* __restrict__ hsh,
    int* __restrict__ posA, int* __restrict__ tokA)
{
  __shared__ int hist[32*256];
  __shared__ int sums[256];
  __shared__ int wtot[4];
  int br = blockIdx.x;
  int t = threadIdx.x;
  const uint8_t* hh = hsh + (size_t)br*LEN;
  uint8_t ub[8];
  #pragma unroll
  for (int i=0;i<8;i++) ub[i] = hh[t*8+i];
  #pragma unroll
  for (int k=0;k<32;k++) hist[k*256+t] = 0;
  __syncthreads();
  #pragma unroll
  for (int i=0;i<8;i++) hist[(int)ub[i]*256 + t] += 1;
  __syncthreads();
  int base = t*32, s0 = 0;
  for (int e=0;e<32;e++) s0 += hist[base+e];
  // parallel exclusive scan of s0 across 256 threads
  int x = s0;
  #pragma unroll
  for (int off=1; off<64; off<<=1){
    int y = __shfl_up(x, off);
    if ((t & 63) >= off) x += y;
  }
  if ((t & 63) == 63) wtot[t>>6] = x;
  __syncthreads();
  int add = 0;
  #pragma unroll
  for (int i2=0;i2<4;i2++) add += (i2 < (t>>6)) ? wtot[i2] : 0;
  int run = x - s0 + add;           // exclusive prefix of per-thread totals
  for (int e=0;e<32;e++){ int tmp = hist[base+e]; hist[base+e] = run; run += tmp; }
  __syncthreads();
  #pragma unroll
  for (int i=0;i<8;i++){
    int l = t*8+i, k = ub[i];
    int p = hist[k*256+t]++;
    posA[(size_t)br*LEN + l] = p;
    tokA[(size_t)br*LEN + p] = l | (k << 11);
  }
}

// ---------------- kernel 2b: pack meta = tok | bucket<<11 | chunkcode<<16 ----------------
__global__ __launch_bounds__(256) void k_meta(
    const int* __restrict__ posA, const int* __restrict__ tokA, int* __restrict__ meta)
{
  int idx = blockIdx.x*256 + threadIdx.x;
  int br = idx >> 11;
  int b = br >> 2;
  int raw = tokA[idx];
  int tok = raw & 2047;
  int code = 0;
  #pragma unroll
  for (int r2=0;r2<4;r2++){
    int p = posA[(size_t)(b*4+r2)*LEN + tok];
    code |= (p >> 7) << (4*r2);
  }
  meta[idx] = raw | (code<<16);    // raw already = tok | bucket<<11
}

// ---------------- kernel 3: fused MFMA attention, 32x32x16 version ----------------
// 256 threads = 4 waves; wave w owns q-tile w (32 q) across all 256 keys.
// Per slice (32 keys): [QK + V-transpose + epilogue->Ps] barrier [stage(c+1) + PV].
__global__ __launch_bounds__(256, 3) void k_fattn(
    const uint16_t* __restrict__ fqb, const uint16_t* __restrict__ vbb,
    const int* __restrict__ meta, uint16_t* __restrict__ attb,
    float* __restrict__ rowsum)
{
  __shared__ __align__(16) char smem[39936];
  uint16_t* Ks  = (uint16_t*)smem;               // 32*136*2 = 8704
  uint16_t* Vs2 = (uint16_t*)(smem + 8704);      // 32*136*2 = 8704 (raw V rows)
  uint16_t* VT  = (uint16_t*)(smem + 17408);     // 128*40*2 = 10240 (V^T [d][key])
  uint16_t* Ps  = (uint16_t*)(smem + 27648);     // 128*40*2 = 10240 (P [q][key])
  uint2*    km2 = (uint2*)(smem + 37888);        // 256*8    = 2048
  uint16_t* Qb  = (uint16_t*)smem;               // epilogue alias: 64*136*2 = 17408 (Ks+Vs2)

  int bid = blockIdx.x;
  int n = bid & 15, r = (bid>>4)&3, b = bid>>6;
  int t = threadIdx.x;
  int w = t >> 6, lane = t & 63, l31 = lane & 31, h = lane >> 5;
  int br = b*RND + r;
  int sbase = br*LEN, qs0 = n*BL2;
  size_t gbase = (size_t)b*LEN;

  { // key metadata for the 256-key window
    int sk = (t < BL2) ? (((n+NB2-1)&15)*BL2 + t) : (n*BL2 + t - BL2);
    int km = meta[sbase + sk];
    uint32_t ck = ((uint32_t)km) >> 16;
    uint32_t ckp1 = ((ck & 0x7777u) + 0x1111u) ^ (ck & 0x8888u);  // nibble +1 mod 16
    uint2 kv; kv.x = (uint32_t)(km & 0xFFFF); kv.y = ck | (ckp1 << 16);
    km2[t] = kv;
  }
  int mq = meta[sbase + qs0 + w*32 + l31];     // this lane's q (2 lanes per q, h split)
  uint32_t mq16 = (uint32_t)(mq & 0xFFFF);
  uint32_t cq = ((uint32_t)mq) >> 16;
  short8 qf[8];                                 // Q as B-operand: k = h*8+j, base dc*16
  {
    const uint16_t* qrow = fqb + (gbase + (mq & 2047))*DK + h*8;
    #pragma unroll
    for (int dc=0;dc<8;dc++) qf[dc] = *(const short8*)(qrow + dc*16);
  }

  f32x16 O[4];
  #pragma unroll
  for (int i=0;i<4;i++)
    #pragma unroll
    for (int j=0;j<16;j++) O[i][j] = 0.f;
  float rsp = 0.f;

  int srow = t >> 3, sgp = t & 7;              // staging: 32 rows x 8 granule-pairs
  __syncthreads();                              // km2 visible
  { // stage slice 0
    int tok = (int)(km2[srow].x & 2047u);
    const uint16_t* fr = fqb + (gbase + tok)*DK;
    const uint16_t* vr = vbb + (gbase + tok)*DK;
    #pragma unroll
    for (int i=0;i<2;i++){
      int ge = sgp*2 + i;
      *(uint4*)(Ks  + srow*136 + ge*8) = *(const uint4*)(fr + ge*8);
      *(uint4*)(Vs2 + srow*136 + ge*8) = *(const uint4*)(vr + ge*8);
    }
  }

  int d2 = t >> 1, kh = t & 1;                 // transpose coords: d row, key half

  for (int c=0;c<8;c++){
    __syncthreads();
    // ---- S^T = K * Q^T (32x32x16): A = K rows (LDS), B = Q (registers) ----
    f32x16 S;
    #pragma unroll
    for (int j=0;j<16;j++) S[j] = 0.f;
    #pragma unroll
    for (int dc=0;dc<8;dc++){
      short8 a = *(const short8*)(Ks + l31*136 + dc*16 + h*8);
      S = __builtin_amdgcn_mfma_f32_32x32x16_bf16(a, qf[dc], S, 0, 0, 0);
    }
    // ---- V transpose Vs2[key][d] -> VT[d][key] (conflict-free: banks 4j + d/4) ----
    {
      uint16_t tmp[16];
      #pragma unroll
      for (int jj=0;jj<16;jj++) tmp[jj] = Vs2[(kh*16 + jj)*136 + d2];
      *(uint4*)(VT + d2*40 + kh*16)     = *(uint4*)(tmp);
      *(uint4*)(VT + d2*40 + kh*16 + 8) = *(uint4*)(tmp + 8);
    }
    // ---- epilogue: lane owns q = w*32+l31, 16 key-rows = rr + 8g + 4h ----
    #pragma unroll
    for (int g=0; g<4; g++){
      uint32_t uu[4];
      #pragma unroll
      for (int rr=0; rr<4; rr++){
        int key = rr + 8*g + 4*h;
        uint2 kv = km2[c*32 + key];
        uint32_t km16 = kv.x;
        uint32_t ck   = kv.y & 0xFFFFu;
        uint32_t ckp1 = kv.y >> 16;
        uint32_t xr = mq16 ^ km16;
        uint32_t x1 = cq ^ ck, x2 = cq ^ ckp1;
        uint32_t h1 = ~(((x1 & 0x7777u) + 0x7777u) | x1) & 0x8888u;
        uint32_t h2 = ~(((x2 & 0x7777u) + 0x7777u) | x2) & 0x8888u;
        uint32_t msum = (h1 >> 3) + (h2 >> 3);
        uint32_t cnt = ((msum * 0x1111u) >> 12) & 15u;     // dup count 1..4
        float rcf = __builtin_amdgcn_rcpf((float)cnt);
        float Sv = S[g*4 + rr];
        float arg = fmaf(Sv, 0.12751743f, -0.14426950f);   // (S/sqrt(128)-0.1)*log2e
        arg = (xr == 0u) ? -43.425121f : arg;              // self
        bool kill = (xr >= 2048u) | (mq16 < km16);
        arg = kill ? -1e9f : arg;
        float e = __builtin_amdgcn_exp2f(arg) * rcf;
        rsp += e;
        uu[rr] = __float_as_uint(e);
      }
      uint2 pw;
      pw.x = __builtin_amdgcn_perm(uu[1], uu[0], 0x07060302);  // truncate-pack bf16x2
      pw.y = __builtin_amdgcn_perm(uu[3], uu[2], 0x07060302);
      *(uint2*)(Ps + (w*32 + l31)*40 + 8*g + 4*h) = pw;
    }
    __syncthreads();
    // ---- stage slice c+1 (loads issue first, hide under PV) ----
    if (c < 7){
      int tok = (int)(km2[(c+1)*32 + srow].x & 2047u);
      const uint16_t* fr = fqb + (gbase + tok)*DK;
      const uint16_t* vr = vbb + (gbase + tok)*DK;
      #pragma unroll
      for (int i=0;i<2;i++){
        int ge = sgp*2 + i;
        *(uint4*)(Ks  + srow*136 + ge*8) = *(const uint4*)(fr + ge*8);
        *(uint4*)(Vs2 + srow*136 + ge*8) = *(const uint4*)(vr + ge*8);
      }
    }
    // ---- O^T += V^T * P^T: A = V^T rows (d), B = P rows (q) ----
    short8 pb0 = *(const short8*)(Ps + (w*32 + l31)*40      + h*8);
    short8 pb1 = *(const short8*)(Ps + (w*32 + l31)*40 + 16 + h*8);
    #pragma unroll
    for (int dt=0; dt<4; dt++){
      short8 a0 = *(const short8*)(VT + (dt*32 + l31)*40      + h*8);
      short8 a1 = *(const short8*)(VT + (dt*32 + l31)*40 + 16 + h*8);
      O[dt] = __builtin_amdgcn_mfma_f32_32x32x16_bf16(a0, pb0, O[dt], 0, 0, 0);
      O[dt] = __builtin_amdgcn_mfma_f32_32x32x16_bf16(a1, pb1, O[dt], 0, 0, 0);
    }
  }
  rsp += __shfl_xor(rsp, 32);
  if (lane < 32) rowsum[sbase + qs0 + w*32 + l31] = rsp;
  // ---- output: D rows = d (= rr+8g+4h + dt*32), cols = q (= l31). Bounce via Qb. ----
  #pragma unroll
  for (int p=0;p<2;p++){
    __syncthreads();
    if ((w>>1) == p){
      int qloc = (w&1)*32 + l31;
      #pragma unroll
      for (int dt=0; dt<4; dt++)
        #pragma unroll
        for (int g=0; g<4; g++){
          uint2 ow;
          ow.x = pk2(O[dt][g*4+0], O[dt][g*4+1]);
          ow.y = pk2(O[dt][g*4+2], O[dt][g*4+3]);
          *(uint2*)(Qb + qloc*136 + dt*32 + 8*g + 4*h) = ow;
        }
    }
    __syncthreads();
    #pragma unroll
    for (int i=0;i<4;i++){
      int ch = t + i*256;
      int row = ch >> 4, c16 = ch & 15;
      uint4 u = *(const uint4*)(Qb + row*136 + c16*8);
      *(uint4*)(attb + ((size_t)(sbase + qs0 + p*64 + row))*DK + c16*8) = u;
    }
  }
}

// ---------------- kernel 4: gather rounds to original order, normalize ----------------
__global__ __launch_bounds__(256) void k_out(const uint16_t* __restrict__ attb,
    const float* __restrict__ rowsum, const int* __restrict__ posA,
    float* __restrict__ out)
{
  int idx = blockIdx.x*2 + (threadIdx.x >> 7);   // b*LEN + l
  int tt = threadIdx.x & 127;
  int b = idx >> 11;
  int l = idx & (LEN-1);
  float num = 0.f, den = 0.f;
  #pragma unroll
  for (int r=0;r<4;r++){
    int sp = posA[(size_t)(b*RND+r)*LEN + l];
    size_t ro = ((size_t)(b*RND+r)*LEN + sp);
    num += bflo((uint32_t)attb[ro*DK + tt]);
    den += rowsum[ro];
  }
  out[(size_t)idx*DK + tt] = num / den;
}

extern "C" void kernel_launch(void* const* d_in, const int* in_sizes, int n_in,
                              void* d_out, int out_size, void* d_ws, size_t ws_size,
                              hipStream_t stream)
{
  const float* q  = (const float*)d_in[0];
  const float* v  = (const float*)d_in[1];
  const float* rm = (const float*)d_in[3];
  float* out = (float*)d_out;

  char* w = (char*)d_ws;
  uint16_t* fqb    = (uint16_t*)(w + 0);               // 8 MiB normalized q, bf16
  uint16_t* vbb    = (uint16_t*)(w + 8388608);         // 8 MiB value, bf16
  uint8_t*  hsh    = (uint8_t*) (w + 16777216);        // 128 KiB
  int*      posA   = (int*)     (w + 16908288);        // 512 KiB
  int*      tokA   = (int*)     (w + 17432576);        // 512 KiB
  int*      meta   = (int*)     (w + 17956864);        // 512 KiB
  float*    rowsum = (float*)   (w + 18481152);        // 512 KiB
  uint16_t* attb   = (uint16_t*)(w + 19005440);        // 32 MiB unnormalized O, bf16

  k_hash <<<dim3(BH*32),          dim3(256), 0, stream>>>(q, v, rm, fqb, vbb, hsh);
  k_sort <<<dim3(BH*RND),         dim3(256), 0, stream>>>(hsh, posA, tokA);
  k_meta <<<dim3(BH*RND*LEN/256), dim3(256), 0, stream>>>(posA, tokA, meta);
  k_fattn<<<dim3(BH*RND*NB2),     dim3(256), 0, stream>>>(fqb, vbb, meta, attb, rowsum);
  k_out  <<<dim3(BH*LEN/2),       dim3(256), 0, stream>>>(attb, rowsum, posA, out);
}

// Round 8
// 165.911 us; speedup vs baseline: 4.7028x; 1.0446x over previous
//
#include <hip/hip_runtime.h>
#include <hip/hip_bf16.h>
#include <stdint.h>

constexpr int BH  = 16;    // batch*head
constexpr int LEN = 2048;
constexpr int DK  = 128;
constexpr int RND = 4;
constexpr int NB2 = 16;    // n_buckets/2 (chunk count)
constexpr int BL2 = 128;   // queries per chunk

typedef __attribute__((ext_vector_type(8)))  short short8;
typedef __attribute__((ext_vector_type(4)))  float f32x4;
typedef __attribute__((ext_vector_type(16))) float f32x16;

__device__ __forceinline__ float bflo(uint32_t u){ return __uint_as_float(u << 16); }
__device__ __forceinline__ uint16_t f2b(float x){
  uint32_t u = __float_as_uint(x);
  return (uint16_t)((u + 0x7fffu + ((u >> 16) & 1u)) >> 16);   // RNE
}
__device__ __forceinline__ uint32_t pk2(float a, float b){
  return (uint32_t)f2b(a) | ((uint32_t)f2b(b) << 16);
}

// ---------------- kernel 1: 64 tokens/block; register-tiled fp32 GEMM hash ----------------
// rm_s [d][col] (native layout), qT [d][tok]. Thread (tt,cc) computes 4 tok x 4 col.
// Round r == wave index; argmax combined across col-subgroups via shfl_xor(16/32).
__global__ __launch_bounds__(256) void k_hash(const float* __restrict__ q,
    const float* __restrict__ v, const float* __restrict__ rm,
    uint16_t* __restrict__ fqb, uint16_t* __restrict__ vbb,
    uint8_t* __restrict__ hsh)
{
  __shared__ float rm_s[128*64];    // 32 KB
  __shared__ float qT[128*64];      // 32 KB
  __shared__ float invn_s[64];
  int b = blockIdx.x >> 5, chunk = blockIdx.x & 31;
  int t = threadIdx.x;
  // stage rm straight (it is [d][r][k] row-major = [d][64 cols])
  const float4* rm4 = (const float4*)(rm + (size_t)b*8192);
  #pragma unroll
  for (int i=0;i<8;i++) ((float4*)rm_s)[i*256 + t] = rm4[i*256 + t];
  // stage q (normalize) + bf16 conversions; token tl, d-slice qq*32..+31
  int tl = t >> 2, qq = t & 3;
  int tok = chunk*64 + tl;
  size_t ro = ((size_t)b*LEN + tok)*DK;
  float qs[32];
  float ss = 0.f;
  #pragma unroll
  for (int i=0;i<8;i++){
    float4 w = *(const float4*)(q + ro + qq*32 + i*4);
    qs[i*4]=w.x; qs[i*4+1]=w.y; qs[i*4+2]=w.z; qs[i*4+3]=w.w;
    ss += w.x*w.x + w.y*w.y + w.z*w.z + w.w*w.w;
  }
  ss += __shfl_xor(ss,1); ss += __shfl_xor(ss,2);
  float rn = 1.0f / sqrtf(ss);
  #pragma unroll
  for (int i=0;i<32;i++) qs[i] *= rn;
  #pragma unroll
  for (int i=0;i<4;i++){
    uint4 u;
    u.x = pk2(qs[i*8+0], qs[i*8+1]); u.y = pk2(qs[i*8+2], qs[i*8+3]);
    u.z = pk2(qs[i*8+4], qs[i*8+5]); u.w = pk2(qs[i*8+6], qs[i*8+7]);
    *(uint4*)(fqb + ro + qq*32 + i*8) = u;
  }
  #pragma unroll
  for (int i=0;i<4;i++){
    float4 a = *(const float4*)(v + ro + qq*32 + i*8);
    float4 c = *(const float4*)(v + ro + qq*32 + i*8 + 4);
    uint4 u;
    u.x = pk2(a.x,a.y); u.y = pk2(a.z,a.w); u.z = pk2(c.x,c.y); u.w = pk2(c.z,c.w);
    *(uint4*)(vbb + ro + qq*32 + i*8) = u;
  }
  #pragma unroll
  for (int i=0;i<32;i++) qT[(qq*32+i)*64 + tl] = qs[i];
  __syncthreads();
  if (t < 64){                      // rm column inverse norms (banks spread by t%32)
    float s2 = 0.f;
    for (int d=0; d<128; d++){ float w = rm_s[d*64+t]; s2 += w*w; }
    invn_s[t] = 1.0f / sqrtf(s2);
  }
  // GEMM: 4x4 register tile
  int tt = t & 15, cc = t >> 4;
  f32x4 a0={0,0,0,0}, a1={0,0,0,0}, a2={0,0,0,0}, a3={0,0,0,0};
  const float* qTp = qT   + tt*4;
  const float* rmp = rm_s + cc*4;
  #pragma unroll 8
  for (int d=0; d<128; d++){
    float4 qv = *(const float4*)(qTp + d*64);
    float4 rv = *(const float4*)(rmp + d*64);
    a0[0]+=qv.x*rv.x; a0[1]+=qv.x*rv.y; a0[2]+=qv.x*rv.z; a0[3]+=qv.x*rv.w;
    a1[0]+=qv.y*rv.x; a1[1]+=qv.y*rv.y; a1[2]+=qv.y*rv.z; a1[3]+=qv.y*rv.w;
    a2[0]+=qv.z*rv.x; a2[1]+=qv.z*rv.y; a2[2]+=qv.z*rv.z; a2[3]+=qv.z*rv.w;
    a3[0]+=qv.w*rv.x; a3[1]+=qv.w*rv.y; a3[2]+=qv.w*rv.z; a3[3]+=qv.w*rv.w;
  }
  __syncthreads();                  // invn_s ready
  float rin[4];
  #pragma unroll
  for (int j=0;j<4;j++) rin[j] = invn_s[cc*4+j];
  int r = cc >> 2;                  // round == wave
  int m = cc & 3;                   // col subgroup
  float bp[4], bn[4]; int bip[4], bin[4];
  #pragma unroll
  for (int i=0;i<4;i++){ bp[i]=-1e30f; bn[i]=-1e30f; bip[i]=0; bin[i]=16; }
  #pragma unroll
  for (int j=0;j<4;j++){
    int col = m*4 + j;              // k within round, 0..15
    #pragma unroll
    for (int i=0;i<4;i++){
      float hv = (i==0?a0[j]:i==1?a1[j]:i==2?a2[j]:a3[j]) * rin[j];
      if ( hv > bp[i]){ bp[i] =  hv; bip[i] = col; }
      if (-hv > bn[i]){ bn[i] = -hv; bin[i] = col + 16; }
    }
  }
  #pragma unroll
  for (int off=16; off<=32; off<<=1){
    #pragma unroll
    for (int i=0;i<4;i++){
      float op = __shfl_xor(bp[i], off); int oip = __shfl_xor(bip[i], off);
      if (op > bp[i] || (op == bp[i] && oip < bip[i])){ bp[i]=op; bip[i]=oip; }
      float on = __shfl_xor(bn[i], off); int oin = __shfl_xor(bin[i], off);
      if (on > bn[i] || (on == bn[i] && oin < bin[i])){ bn[i]=on; bin[i]=oin; }
    }
  }
  if (m == 0){                      // one writer per (round, token-group)
    uint32_t pk = 0;
    #pragma unroll
    for (int i=0;i<4;i++){
      int bidx = (bn[i] > bp[i]) ? bin[i] : bip[i];
      pk |= (uint32_t)bidx << (8*i);
    }
    *(uint32_t*)(hsh + ((size_t)(b*RND + r))*LEN + chunk*64 + tt*4) = pk;
  }
}

// ---------------- kernel 2: stable counting sort per (b,r), parallel scan ----------------
__global__ __launch_bounds__(256) void k_sort(const uint8_t* __restrict__ hsh,
    int* __restrict__ posA, int* __restrict__ tokA)
{
  __shared__ int hist[32*256];
  __shared__ int wtot[4];
  int br = blockIdx.x;
  int t = threadIdx.x;
  const uint8_t* hh = hsh + (size_t)br*LEN;
  uint8_t ub[8];
  #pragma unroll
  for (int i=0;i<8;i++) ub[i] = hh[t*8+i];
  #pragma unroll
  for (int k=0;k<32;k++) hist[k*256+t] = 0;
  __syncthreads();
  #pragma unroll
  for (int i=0;i<8;i++) hist[(int)ub[i]*256 + t] += 1;
  __syncthreads();
  int base = t*32, s0 = 0;
  for (int e=0;e<32;e++) s0 += hist[base+e];
  int x = s0;
  #pragma unroll
  for (int off=1; off<64; off<<=1){
    int y = __shfl_up(x, off);
    if ((t & 63) >= off) x += y;
  }
  if ((t & 63) == 63) wtot[t>>6] = x;
  __syncthreads();
  int add = 0;
  #pragma unroll
  for (int i2=0;i2<4;i2++) add += (i2 < (t>>6)) ? wtot[i2] : 0;
  int run = x - s0 + add;
  for (int e=0;e<32;e++){ int tmp = hist[base+e]; hist[base+e] = run; run += tmp; }
  __syncthreads();
  #pragma unroll
  for (int i=0;i<8;i++){
    int l = t*8+i, k = ub[i];
    int p = hist[k*256+t]++;
    posA[(size_t)br*LEN + l] = p;
    tokA[(size_t)br*LEN + p] = l | (k << 11);
  }
}

// ---------------- kernel 2b: pack meta = tok | bucket<<11 | chunkcode<<16 ----------------
__global__ __launch_bounds__(256) void k_meta(
    const int* __restrict__ posA, const int* __restrict__ tokA, int* __restrict__ meta)
{
  int idx = blockIdx.x*256 + threadIdx.x;
  int br = idx >> 11;
  int b = br >> 2;
  int raw = tokA[idx];
  int tok = raw & 2047;
  int code = 0;
  #pragma unroll
  for (int r2=0;r2<4;r2++){
    int p = posA[(size_t)(b*4+r2)*LEN + tok];
    code |= (p >> 7) << (4*r2);
  }
  meta[idx] = raw | (code<<16);
}

// ---------------- kernel 3: fused MFMA attention, 32x32x16 ----------------
__global__ __launch_bounds__(256, 3) void k_fattn(
    const uint16_t* __restrict__ fqb, const uint16_t* __restrict__ vbb,
    const int* __restrict__ meta, uint16_t* __restrict__ attb,
    float* __restrict__ rowsum)
{
  __shared__ __align__(16) char smem[39936];
  uint16_t* Ks  = (uint16_t*)smem;               // 32*136*2 = 8704
  uint16_t* Vs2 = (uint16_t*)(smem + 8704);      // 32*136*2 = 8704
  uint16_t* VT  = (uint16_t*)(smem + 17408);     // 128*40*2 = 10240
  uint16_t* Ps  = (uint16_t*)(smem + 27648);     // 128*40*2 = 10240
  uint2*    km2 = (uint2*)(smem + 37888);        // 256*8    = 2048
  uint16_t* Qb  = (uint16_t*)smem;               // epilogue alias

  int bid = blockIdx.x;
  int n = bid & 15, r = (bid>>4)&3, b = bid>>6;
  int t = threadIdx.x;
  int w = t >> 6, lane = t & 63, l31 = lane & 31, h = lane >> 5;
  int br = b*RND + r;
  int sbase = br*LEN, qs0 = n*BL2;
  size_t gbase = (size_t)b*LEN;

  {
    int sk = (t < BL2) ? (((n+NB2-1)&15)*BL2 + t) : (n*BL2 + t - BL2);
    int km = meta[sbase + sk];
    uint32_t ck = ((uint32_t)km) >> 16;
    uint32_t ckp1 = ((ck & 0x7777u) + 0x1111u) ^ (ck & 0x8888u);
    uint2 kv; kv.x = (uint32_t)(km & 0xFFFF); kv.y = ck | (ckp1 << 16);
    km2[t] = kv;
  }
  int mq = meta[sbase + qs0 + w*32 + l31];
  uint32_t mq16 = (uint32_t)(mq & 0xFFFF);
  uint32_t cq = ((uint32_t)mq) >> 16;
  short8 qf[8];
  {
    const uint16_t* qrow = fqb + (gbase + (mq & 2047))*DK + h*8;
    #pragma unroll
    for (int dc=0;dc<8;dc++) qf[dc] = *(const short8*)(qrow + dc*16);
  }

  f32x16 O[4];
  #pragma unroll
  for (int i=0;i<4;i++)
    #pragma unroll
    for (int j=0;j<16;j++) O[i][j] = 0.f;
  float rsp = 0.f;

  int srow = t >> 3, sgp = t & 7;
  __syncthreads();
  {
    int tok = (int)(km2[srow].x & 2047u);
    const uint16_t* fr = fqb + (gbase + tok)*DK;
    const uint16_t* vr = vbb + (gbase + tok)*DK;
    #pragma unroll
    for (int i=0;i<2;i++){
      int ge = sgp*2 + i;
      *(uint4*)(Ks  + srow*136 + ge*8) = *(const uint4*)(fr + ge*8);
      *(uint4*)(Vs2 + srow*136 + ge*8) = *(const uint4*)(vr + ge*8);
    }
  }

  int d2 = t >> 1, kh = t & 1;

  for (int c=0;c<8;c++){
    __syncthreads();
    // ---- S^T = K * Q^T ----
    f32x16 S;
    #pragma unroll
    for (int j=0;j<16;j++) S[j] = 0.f;
    #pragma unroll
    for (int dc=0;dc<8;dc++){
      short8 a = *(const short8*)(Ks + l31*136 + dc*16 + h*8);
      S = __builtin_amdgcn_mfma_f32_32x32x16_bf16(a, qf[dc], S, 0, 0, 0);
    }
    // ---- V transpose ----
    {
      uint16_t tmp[16];
      #pragma unroll
      for (int jj=0;jj<16;jj++) tmp[jj] = Vs2[(kh*16 + jj)*136 + d2];
      *(uint4*)(VT + d2*40 + kh*16)     = *(uint4*)(tmp);
      *(uint4*)(VT + d2*40 + kh*16 + 8) = *(uint4*)(tmp + 8);
    }
    // ---- epilogue ----
    #pragma unroll
    for (int g=0; g<4; g++){
      const uint4* kp = (const uint4*)(km2 + c*32 + 8*g + 4*h);
      uint4 ka = kp[0], kb = kp[1];
      uint32_t kmv[4] = {ka.x, ka.z, kb.x, kb.z};
      uint32_t cky[4] = {ka.y, ka.w, kb.y, kb.w};
      uint32_t uu[4];
      #pragma unroll
      for (int rr=0; rr<4; rr++){
        uint32_t km16 = kmv[rr];
        uint32_t ck   = cky[rr] & 0xFFFFu;
        uint32_t ckp1 = cky[rr] >> 16;
        uint32_t xr = mq16 ^ km16;
        uint32_t x1 = cq ^ ck, x2 = cq ^ ckp1;
        uint32_t h1 = ~(((x1 & 0x7777u) + 0x7777u) | x1) & 0x8888u;
        uint32_t h2 = ~(((x2 & 0x7777u) + 0x7777u) | x2) & 0x8888u;
        uint32_t msum = (h1 >> 3) + (h2 >> 3);
        uint32_t cnt = ((msum * 0x1111u) >> 12) & 15u;
        float rcf = __builtin_amdgcn_rcpf((float)cnt);
        float Sv = S[g*4 + rr];
        float arg = fmaf(Sv, 0.12751743f, -0.14426950f);
        arg = (xr == 0u) ? -43.425121f : arg;
        bool kill = (xr >= 2048u) | (mq16 < km16);
        arg = kill ? -1e9f : arg;
        float e = __builtin_amdgcn_exp2f(arg) * rcf;
        rsp += e;
        uu[rr] = __float_as_uint(e);
      }
      uint2 pw;
      pw.x = __builtin_amdgcn_perm(uu[1], uu[0], 0x07060302);
      pw.y = __builtin_amdgcn_perm(uu[3], uu[2], 0x07060302);
      *(uint2*)(Ps + (w*32 + l31)*40 + 8*g + 4*h) = pw;
    }
    __syncthreads();
    // ---- stage slice c+1 ----
    if (c < 7){
      int tok = (int)(km2[(c+1)*32 + srow].x & 2047u);
      const uint16_t* fr = fqb + (gbase + tok)*DK;
      const uint16_t* vr = vbb + (gbase + tok)*DK;
      #pragma unroll
      for (int i=0;i<2;i++){
        int ge = sgp*2 + i;
        *(uint4*)(Ks  + srow*136 + ge*8) = *(const uint4*)(fr + ge*8);
        *(uint4*)(Vs2 + srow*136 + ge*8) = *(const uint4*)(vr + ge*8);
      }
    }
    // ---- O^T += V^T * P^T ----
    short8 pb0 = *(const short8*)(Ps + (w*32 + l31)*40      + h*8);
    short8 pb1 = *(const short8*)(Ps + (w*32 + l31)*40 + 16 + h*8);
    #pragma unroll
    for (int dt=0; dt<4; dt++){
      short8 va0 = *(const short8*)(VT + (dt*32 + l31)*40      + h*8);
      short8 va1 = *(const short8*)(VT + (dt*32 + l31)*40 + 16 + h*8);
      O[dt] = __builtin_amdgcn_mfma_f32_32x32x16_bf16(va0, pb0, O[dt], 0, 0, 0);
      O[dt] = __builtin_amdgcn_mfma_f32_32x32x16_bf16(va1, pb1, O[dt], 0, 0, 0);
    }
  }
  rsp += __shfl_xor(rsp, 32);
  if (lane < 32) rowsum[sbase + qs0 + w*32 + l31] = rsp;
  #pragma unroll
  for (int p=0;p<2;p++){
    __syncthreads();
    if ((w>>1) == p){
      int qloc = (w&1)*32 + l31;
      #pragma unroll
      for (int dt=0; dt<4; dt++)
        #pragma unroll
        for (int g=0; g<4; g++){
          uint2 ow;
          ow.x = pk2(O[dt][g*4+0], O[dt][g*4+1]);
          ow.y = pk2(O[dt][g*4+2], O[dt][g*4+3]);
          *(uint2*)(Qb + qloc*136 + dt*32 + 8*g + 4*h) = ow;
        }
    }
    __syncthreads();
    #pragma unroll
    for (int i=0;i<4;i++){
      int ch = t + i*256;
      int row = ch >> 4, c16 = ch & 15;
      uint4 u = *(const uint4*)(Qb + row*136 + c16*8);
      *(uint4*)(attb + ((size_t)(sbase + qs0 + p*64 + row))*DK + c16*8) = u;
    }
  }
}

// ---------------- kernel 4: gather rounds to original order, normalize ----------------
__global__ __launch_bounds__(256) void k_out(const uint16_t* __restrict__ attb,
    const float* __restrict__ rowsum, const int* __restrict__ posA,
    float* __restrict__ out)
{
  int idx = blockIdx.x*2 + (threadIdx.x >> 7);   // b*LEN + l
  int tt = threadIdx.x & 127;
  int b = idx >> 11;
  int l = idx & (LEN-1);
  float num = 0.f, den = 0.f;
  #pragma unroll
  for (int r=0;r<4;r++){
    int sp = posA[(size_t)(b*RND+r)*LEN + l];
    size_t ro = ((size_t)(b*RND+r)*LEN + sp);
    num += bflo((uint32_t)attb[ro*DK + tt]);
    den += rowsum[ro];
  }
  out[(size_t)idx*DK + tt] = num / den;
}

extern "C" void kernel_launch(void* const* d_in, const int* in_sizes, int n_in,
                              void* d_out, int out_size, void* d_ws, size_t ws_size,
                              hipStream_t stream)
{
  const float* q  = (const float*)d_in[0];
  const float* v  = (const float*)d_in[1];
  const float* rm = (const float*)d_in[3];
  float* out = (float*)d_out;

  char* w = (char*)d_ws;
  uint16_t* fqb    = (uint16_t*)(w + 0);               // 8 MiB normalized q, bf16
  uint16_t* vbb    = (uint16_t*)(w + 8388608);         // 8 MiB value, bf16
  uint8_t*  hsh    = (uint8_t*) (w + 16777216);        // 128 KiB
  int*      posA   = (int*)     (w + 16908288);        // 512 KiB
  int*      tokA   = (int*)     (w + 17432576);        // 512 KiB
  int*      meta   = (int*)     (w + 17956864);        // 512 KiB
  float*    rowsum = (float*)   (w + 18481152);        // 512 KiB
  uint16_t* attb   = (uint16_t*)(w + 19005440);        // 32 MiB unnormalized O, bf16

  k_hash <<<dim3(BH*32),          dim3(256), 0, stream>>>(q, v, rm, fqb, vbb, hsh);
  k_sort <<<dim3(BH*RND),         dim3(256), 0, stream>>>(hsh, posA, tokA);
  k_meta <<<dim3(BH*RND*LEN/256), dim3(256), 0, stream>>>(posA, tokA, meta);
  k_fattn<<<dim3(BH*RND*NB2),     dim3(256), 0, stream>>>(fqb, vbb, meta, attb, rowsum);
  k_out  <<<dim3(BH*LEN/2),       dim3(256), 0, stream>>>(attb, rowsum, posA, out);
}